// Round 14
// baseline (636.565 us; speedup 1.0000x reference)
//
#include <hip/hip_runtime.h>
#include <hip/hip_bf16.h>
#include <hip/hip_fp16.h>
#include <cstdint>
#include <cstddef>

// B=64, D=512, T=1024, L=512
// prep:  xt[b][t][d] bf16 ; W1t[l][d] bf16 ; W2t[n=1536][k=1024] bf16 ; il bf16
// K1:    z = LN(cos(xt @ rff_w + b))  FUSED (BM=64 x BN=512 full-row, BK=64
//        swizzled staging, named accs; LN epilogue = r6-verified math)
// K2:    uniform 6-block decomposition per 128-row tile (r12-verified)
// scan (segmented): k3a summaries -> k3b combine -> k3c emit + transpose
//
// LESSONS: (r4-r6) acc arrays are NOT SROA-promoted -> scratch RMW; use NAMED
// accumulators. (r8) XOR swizzle both-sides -> bank conflicts 2.5e7 -> 0.
// (r9 FAIL) loads in flight across raw s_barriers race (vmcnt is per-wave).
// (r10 FAIL) explicit dbuf halved blocks/CU; inter-block overlap already hid
// stage latency. (r13 FAIL) stray invalid macro line -> compile error.

typedef float f32x4 __attribute__((ext_vector_type(4)));
typedef short s16x8 __attribute__((ext_vector_type(8)));

__device__ __forceinline__ void gload_lds16(const void* g, void* l) {
  __builtin_amdgcn_global_load_lds(
      (const __attribute__((address_space(1))) void*)g,
      (__attribute__((address_space(3))) void*)l, 16, 0, 0);
}
__device__ __forceinline__ ushort f2bf(float f) {
  uint32_t u = __float_as_uint(f);
  return (ushort)((u + 0x7FFF + ((u >> 16) & 1)) >> 16);  // RNE
}
__device__ __forceinline__ float bf2f(ushort s) {
  return __uint_as_float(((uint32_t)s) << 16);
}
__device__ __forceinline__ ushort f2h(float f) {
  return __half_as_ushort(__float2half(f));
}
__device__ __forceinline__ float h2f(ushort s) {
  return __half2float(__ushort_as_half(s));
}

#define MF(d, a, b) d = __builtin_amdgcn_mfma_f32_16x16x32_bf16(a, b, d, 0, 0, 0);

// ------------------------------------------------ prep: 6 gate weights + W1 + il
__global__ __launch_bounds__(256) void transpose8(
    const float* __restrict__ s0, const float* __restrict__ s1,
    const float* __restrict__ s2, const float* __restrict__ s3,
    const float* __restrict__ s4, const float* __restrict__ s5,
    const float* __restrict__ il, const float* __restrict__ W1,
    ushort* __restrict__ W2t, ushort* __restrict__ ilb,
    ushort* __restrict__ W1t)
{
  const int z = blockIdx.z;
  if (z == 6) {
    if (blockIdx.x == 0 && blockIdx.y == 0) {
      ilb[threadIdx.x] = f2bf(il[threadIdx.x]);
      ilb[threadIdx.x + 256] = f2bf(il[threadIdx.x + 256]);
    }
    return;
  }
  const float* src = z == 0 ? s0 : z == 1 ? s1 : z == 2 ? s2
                   : z == 3 ? s3 : z == 4 ? s4 : z == 5 ? s5 : W1;
  ushort* dst = (z == 7) ? W1t
              : W2t + (size_t)(z >> 1) * 512 * 1024 + (z & 1) * 512;
  const int ld = (z == 7) ? 512 : 1024;
  __shared__ float tile[32][33];
  const int c0 = blockIdx.x * 32, r0 = blockIdx.y * 32;
  const int tx = threadIdx.x & 31, ty = threadIdx.x >> 5;
#pragma unroll
  for (int i = 0; i < 4; ++i)
    tile[ty + i * 8][tx] = src[(size_t)(r0 + ty + i * 8) * 512 + c0 + tx];
  __syncthreads();
#pragma unroll
  for (int i = 0; i < 4; ++i)
    dst[(size_t)(c0 + ty + i * 8) * ld + r0 + tx] = f2bf(tile[tx][ty + i * 8]);
}

// ------------------------------------------------ prep: x[b][d][t] -> xt[b][t][d]
__global__ __launch_bounds__(256) void transpose_x(
    const float* __restrict__ x, ushort* __restrict__ xt)
{
  __shared__ float tile[64][68];
  const int b = blockIdx.z;
  const int t0 = blockIdx.x * 64, d0 = blockIdx.y * 64;
  const float* src = x + ((size_t)b * 512 + d0) * 1024 + t0;
  const int lr_ = threadIdx.x >> 4, lc4 = (threadIdx.x & 15) * 4;
#pragma unroll
  for (int p = 0; p < 4; ++p) {
    const float4 v = *(const float4*)(src + (size_t)(lr_ + p * 16) * 1024 + lc4);
    *(float4*)&tile[lr_ + p * 16][lc4] = v;
  }
  __syncthreads();
  const int tt = threadIdx.x >> 2, dc = (threadIdx.x & 3) * 16;
  ushort* dst = xt + ((size_t)b * 1024 + t0 + tt) * 512 + d0 + dc;
  uint4 o1, o2;
  o1.x = (uint)f2bf(tile[dc + 0][tt]) | ((uint)f2bf(tile[dc + 1][tt]) << 16);
  o1.y = (uint)f2bf(tile[dc + 2][tt]) | ((uint)f2bf(tile[dc + 3][tt]) << 16);
  o1.z = (uint)f2bf(tile[dc + 4][tt]) | ((uint)f2bf(tile[dc + 5][tt]) << 16);
  o1.w = (uint)f2bf(tile[dc + 6][tt]) | ((uint)f2bf(tile[dc + 7][tt]) << 16);
  o2.x = (uint)f2bf(tile[dc + 8][tt]) | ((uint)f2bf(tile[dc + 9][tt]) << 16);
  o2.y = (uint)f2bf(tile[dc + 10][tt]) | ((uint)f2bf(tile[dc + 11][tt]) << 16);
  o2.z = (uint)f2bf(tile[dc + 12][tt]) | ((uint)f2bf(tile[dc + 13][tt]) << 16);
  o2.w = (uint)f2bf(tile[dc + 14][tt]) | ((uint)f2bf(tile[dc + 15][tt]) << 16);
  *(uint4*)(dst) = o1;
  *(uint4*)(dst + 8) = o2;
}

// ------------------------------------------------ K1: z = LN(cos(xt@W1t^T+b))
// BM=64 (full 512-col rows), BK=64, 4 waves each 64 rows x 128 cols.
__global__ __launch_bounds__(256, 2) void k1_mfma(
    const ushort* __restrict__ A, const ushort* __restrict__ Bt,
    const float* __restrict__ bias, ushort* __restrict__ Z)
{
  __shared__ __align__(16) short As[64 * 64];     // 8 KB
  __shared__ __align__(16) short Bs[512 * 64];    // 64 KB
  __shared__ float redS[4][64], redS2[4][64], redM[64], redI[64];
  const int tid = threadIdx.x;
  const int lane = tid & 63, wid = tid >> 6;
  const int orig = blockIdx.x;                    // 1024 blocks
  const int swz = (orig & 7) * 128 + (orig >> 3); // bijective XCD swizzle
  const int r0 = swz * 64;
  const int fr = lane & 15, fq = lane >> 4;
  const int lr = lane >> 3;
  const int swz_el = ((lane & 7) ^ lr) * 8;

  // A: wave wid stages rows [wid*16, wid*16+16)
  const int RA = r0 + wid * 16 + lr;
  const ushort* pa0 = A + (size_t)(RA)     * 512 + swz_el;
  const ushort* pa1 = A + (size_t)(RA + 8) * 512 + swz_el;
  // B: wave wid stages rows [wid*128, wid*128+128) as 16 8-row groups
  const ushort* pb = Bt + (size_t)(wid * 128 + lr) * 512 + swz_el;
  char* dA = (char*)As + wid * 2048;
  char* dB = (char*)Bs + wid * 16384;

  const int so0 = ((fq)     ^ (fr & 7)) * 8;
  const int so1 = ((4 + fq) ^ (fr & 7)) * 8;

  f32x4 zz = {0.f,0.f,0.f,0.f};
  f32x4 c00=zz,c01=zz,c02=zz,c03=zz,c04=zz,c05=zz,c06=zz,c07=zz,
        c10=zz,c11=zz,c12=zz,c13=zz,c14=zz,c15=zz,c16=zz,c17=zz,
        c20=zz,c21=zz,c22=zz,c23=zz,c24=zz,c25=zz,c26=zz,c27=zz,
        c30=zz,c31=zz,c32=zz,c33=zz,c34=zz,c35=zz,c36=zz,c37=zz;

#define KS(SO_) { \
    const s16x8 fa0 = *(const s16x8*)&As[(0 * 16 + fr) * 64 + (SO_)]; \
    const s16x8 fa1 = *(const s16x8*)&As[(1 * 16 + fr) * 64 + (SO_)]; \
    const s16x8 fa2 = *(const s16x8*)&As[(2 * 16 + fr) * 64 + (SO_)]; \
    const s16x8 fa3 = *(const s16x8*)&As[(3 * 16 + fr) * 64 + (SO_)]; \
    const s16x8 fb0 = *(const s16x8*)&Bs[(wid * 128 + 0 * 16 + fr) * 64 + (SO_)]; \
    const s16x8 fb1 = *(const s16x8*)&Bs[(wid * 128 + 1 * 16 + fr) * 64 + (SO_)]; \
    const s16x8 fb2 = *(const s16x8*)&Bs[(wid * 128 + 2 * 16 + fr) * 64 + (SO_)]; \
    const s16x8 fb3 = *(const s16x8*)&Bs[(wid * 128 + 3 * 16 + fr) * 64 + (SO_)]; \
    const s16x8 fb4 = *(const s16x8*)&Bs[(wid * 128 + 4 * 16 + fr) * 64 + (SO_)]; \
    const s16x8 fb5 = *(const s16x8*)&Bs[(wid * 128 + 5 * 16 + fr) * 64 + (SO_)]; \
    const s16x8 fb6 = *(const s16x8*)&Bs[(wid * 128 + 6 * 16 + fr) * 64 + (SO_)]; \
    const s16x8 fb7 = *(const s16x8*)&Bs[(wid * 128 + 7 * 16 + fr) * 64 + (SO_)]; \
    MF(c00,fa0,fb0) MF(c01,fa0,fb1) MF(c02,fa0,fb2) MF(c03,fa0,fb3) \
    MF(c04,fa0,fb4) MF(c05,fa0,fb5) MF(c06,fa0,fb6) MF(c07,fa0,fb7) \
    MF(c10,fa1,fb0) MF(c11,fa1,fb1) MF(c12,fa1,fb2) MF(c13,fa1,fb3) \
    MF(c14,fa1,fb4) MF(c15,fa1,fb5) MF(c16,fa1,fb6) MF(c17,fa1,fb7) \
    MF(c20,fa2,fb0) MF(c21,fa2,fb1) MF(c22,fa2,fb2) MF(c23,fa2,fb3) \
    MF(c24,fa2,fb4) MF(c25,fa2,fb5) MF(c26,fa2,fb6) MF(c27,fa2,fb7) \
    MF(c30,fa3,fb0) MF(c31,fa3,fb1) MF(c32,fa3,fb2) MF(c33,fa3,fb3) \
    MF(c34,fa3,fb4) MF(c35,fa3,fb5) MF(c36,fa3,fb6) MF(c37,fa3,fb7) }

  for (int k0 = 0; k0 < 512; k0 += 64) {
    gload_lds16(pa0 + k0, dA);
    gload_lds16(pa1 + k0, dA + 1024);
#pragma unroll
    for (int g = 0; g < 16; ++g)
      gload_lds16(pb + (size_t)g * 8 * 512 + k0, dB + g * 1024);
    __syncthreads();
    KS(so0)
    KS(so1)
    __syncthreads();
  }
#undef KS

  // epilogue: v = cos(acc + bias); per-row sums; LN; direct z store (r6 math)
  f32x4 ps0 = zz, ps1 = zz, ps2 = zz, ps3 = zz;
  f32x4 pq0 = zz, pq1 = zz, pq2 = zz, pq3 = zz;
#define CB(d, mm, n_) { \
    const float bv = bias[wid * 128 + n_ * 16 + fr]; \
    f32x4 t; \
    _Pragma("unroll") for (int j = 0; j < 4; ++j) t[j] = cosf(d[j] + bv); \
    d = t; ps##mm += t; pq##mm += t * t; }
  CB(c00,0,0) CB(c01,0,1) CB(c02,0,2) CB(c03,0,3)
  CB(c04,0,4) CB(c05,0,5) CB(c06,0,6) CB(c07,0,7)
  CB(c10,1,0) CB(c11,1,1) CB(c12,1,2) CB(c13,1,3)
  CB(c14,1,4) CB(c15,1,5) CB(c16,1,6) CB(c17,1,7)
  CB(c20,2,0) CB(c21,2,1) CB(c22,2,2) CB(c23,2,3)
  CB(c24,2,4) CB(c25,2,5) CB(c26,2,6) CB(c27,2,7)
  CB(c30,3,0) CB(c31,3,1) CB(c32,3,2) CB(c33,3,3)
  CB(c34,3,4) CB(c35,3,5) CB(c36,3,6) CB(c37,3,7)
#undef CB

#define RED2(PS, PQ, m_) \
  _Pragma("unroll") for (int j = 0; j < 4; ++j) { \
    float s = PS[j], s2 = PQ[j]; \
    _Pragma("unroll") for (int msk = 1; msk < 16; msk <<= 1) { \
      s += __shfl_xor(s, msk); s2 += __shfl_xor(s2, msk); } \
    if (fr == 0) { \
      redS[wid][m_ * 16 + fq * 4 + j] = s; \
      redS2[wid][m_ * 16 + fq * 4 + j] = s2; } }
  RED2(ps0, pq0, 0)
  RED2(ps1, pq1, 1)
  RED2(ps2, pq2, 2)
  RED2(ps3, pq3, 3)
#undef RED2
  __syncthreads();
  if (tid < 64) {
    const float s  = redS[0][tid] + redS[1][tid] + redS[2][tid] + redS[3][tid];
    const float s2 = redS2[0][tid] + redS2[1][tid] + redS2[2][tid] + redS2[3][tid];
    const float mean = s * (1.f / 512.f);
    const float var = s2 * (1.f / 512.f) - mean * mean;
    redM[tid] = mean;
    redI[tid] = rsqrtf(var + 1e-5f);
  }
  __syncthreads();

  ushort* Zp = Z + (size_t)r0 * 512;
#define ZW(d, m_, n_) { \
    _Pragma("unroll") for (int j = 0; j < 4; ++j) { \
      const int row = m_ * 16 + fq * 4 + j; \
      Zp[(size_t)row * 512 + wid * 128 + n_ * 16 + fr] = \
          f2bf((d[j] - redM[row]) * redI[row]); } }
  ZW(c00,0,0) ZW(c01,0,1) ZW(c02,0,2) ZW(c03,0,3)
  ZW(c04,0,4) ZW(c05,0,5) ZW(c06,0,6) ZW(c07,0,7)
  ZW(c10,1,0) ZW(c11,1,1) ZW(c12,1,2) ZW(c13,1,3)
  ZW(c14,1,4) ZW(c15,1,5) ZW(c16,1,6) ZW(c17,1,7)
  ZW(c20,2,0) ZW(c21,2,1) ZW(c22,2,2) ZW(c23,2,3)
  ZW(c24,2,4) ZW(c25,2,5) ZW(c26,2,6) ZW(c27,2,7)
  ZW(c30,3,0) ZW(c31,3,1) ZW(c32,3,2) ZW(c33,3,3)
  ZW(c34,3,4) ZW(c35,3,5) ZW(c36,3,6) ZW(c37,3,7)
#undef ZW
}

// ------------------------------------------------ K2: uniform 6 blocks per tile
// (r12-verified, unchanged)
__global__ __launch_bounds__(256, 2) void k2_mfma(
    const ushort* __restrict__ Z, const ushort* __restrict__ Wt,
    const ushort* __restrict__ IL,
    const float* __restrict__ biv, const float* __restrict__ bfv,
    const float* __restrict__ bcv,
    ushort* __restrict__ G2, int tc, int Tc, int nwg)
{
  __shared__ __align__(16) short As[128 * 64];    // 16 KB
  __shared__ __align__(16) short Bs0[128 * 64];   // 16 KB
  __shared__ __align__(16) short Bs1[128 * 64];   // 16 KB
  const int tid = threadIdx.x;
  const int lane = tid & 63, wid = tid >> 6;
  const int cpx = nwg >> 3;
  const int orig = blockIdx.x;
  const int swz = (orig & 7) * cpx + (orig >> 3);
  const int bx = swz % 6, by = swz / 6;
  const int nb = Tc >> 7;
  const int b = by / nb, tb = by % nb;
  const int r0g = b * 1024 + tc + tb * 128;
  const int r0c = b * Tc + tb * 128;
  const bool isig = bx < 4;
  const int n0 = isig ? bx * 128 : 0;
  const int fb = bx - 4;
  const int wr = wid >> 1, wc = wid & 1;
  const int fr = lane & 15, fq = lane >> 4;
  const int lr = lane >> 3;
  const int swz_el = ((lane & 7) ^ lr) * 8;

  const int R0 = r0g + wid * 32 + lr;
  const ushort* pa0 = Z + (size_t)(R0)      * 512 + swz_el;
  const ushort* pa1 = Z + (size_t)(R0 + 8)  * 512 + swz_el;
  const ushort* pa2 = Z + (size_t)(R0 + 16) * 512 + swz_el;
  const ushort* pa3 = Z + (size_t)(R0 + 24) * 512 + swz_el;
  const ushort* ph0 = ((((R0)      & 1023) == 0) ? IL : (Z + (size_t)(R0 - 1)  * 512)) + swz_el;
  const ushort* ph1 = ((((R0 + 8)  & 1023) == 0) ? IL : (Z + (size_t)(R0 + 7)  * 512)) + swz_el;
  const ushort* ph2 = ((((R0 + 16) & 1023) == 0) ? IL : (Z + (size_t)(R0 + 15) * 512)) + swz_el;
  const ushort* ph3 = ((((R0 + 24) & 1023) == 0) ? IL : (Z + (size_t)(R0 + 23) * 512)) + swz_el;
  const int RB0 = (isig ? n0 : 512 + fb * 256) + wid * 32 + lr;
  const ushort* pb0 = Wt + (size_t)(RB0)      * 1024 + swz_el;
  const ushort* pb1 = Wt + (size_t)(RB0 + 8)  * 1024 + swz_el;
  const ushort* pb2 = Wt + (size_t)(RB0 + 16) * 1024 + swz_el;
  const ushort* pb3 = Wt + (size_t)(RB0 + 24) * 1024 + swz_el;
  const int RB1 = (isig ? 1024 + n0 : 512 + fb * 256 + 128) + wid * 32 + lr;
  const ushort* pq0 = Wt + (size_t)(RB1)      * 1024 + swz_el;
  const ushort* pq1 = Wt + (size_t)(RB1 + 8)  * 1024 + swz_el;
  const ushort* pq2 = Wt + (size_t)(RB1 + 16) * 1024 + swz_el;
  const ushort* pq3 = Wt + (size_t)(RB1 + 24) * 1024 + swz_el;

  const int so0 = fr * 64 + ((fq)     ^ (fr & 7)) * 8;
  const int so1 = fr * 64 + ((4 + fq) ^ (fr & 7)) * 8;

  f32x4 zz = {0.f,0.f,0.f,0.f};
  f32x4 c00=zz,c01=zz,c02=zz,c03=zz, c10=zz,c11=zz,c12=zz,c13=zz,
        c20=zz,c21=zz,c22=zz,c23=zz, c30=zz,c31=zz,c32=zz,c33=zz;
  f32x4 d00=zz,d01=zz,d02=zz,d03=zz, d10=zz,d11=zz,d12=zz,d13=zz,
        d20=zz,d21=zz,d22=zz,d23=zz, d30=zz,d31=zz,d32=zz,d33=zz;

#define STG8(P0,P1,P2,P3, KO, DST) { \
    char* d_ = (char*)(DST) + wid * 4096; \
    gload_lds16((P0) + (KO), d_);        gload_lds16((P1) + (KO), d_ + 1024); \
    gload_lds16((P2) + (KO), d_ + 2048); gload_lds16((P3) + (KO), d_ + 3072); }

#define RDA(SO) \
    const s16x8 fa0 = *(const s16x8*)&As[wr * 4096 + 0 * 1024 + (SO)]; \
    const s16x8 fa1 = *(const s16x8*)&As[wr * 4096 + 1 * 1024 + (SO)]; \
    const s16x8 fa2 = *(const s16x8*)&As[wr * 4096 + 2 * 1024 + (SO)]; \
    const s16x8 fa3 = *(const s16x8*)&As[wr * 4096 + 3 * 1024 + (SO)];

#define RDB(BS, SO) \
    const s16x8 fb0 = *(const s16x8*)&(BS)[wc * 4096 + 0 * 1024 + (SO)]; \
    const s16x8 fb1 = *(const s16x8*)&(BS)[wc * 4096 + 1 * 1024 + (SO)]; \
    const s16x8 fb2 = *(const s16x8*)&(BS)[wc * 4096 + 2 * 1024 + (SO)]; \
    const s16x8 fb3 = *(const s16x8*)&(BS)[wc * 4096 + 3 * 1024 + (SO)];

#define MMC \
    MF(c00,fa0,fb0) MF(c01,fa0,fb1) MF(c02,fa0,fb2) MF(c03,fa0,fb3) \
    MF(c10,fa1,fb0) MF(c11,fa1,fb1) MF(c12,fa1,fb2) MF(c13,fa1,fb3) \
    MF(c20,fa2,fb0) MF(c21,fa2,fb1) MF(c22,fa2,fb2) MF(c23,fa2,fb3) \
    MF(c30,fa3,fb0) MF(c31,fa3,fb1) MF(c32,fa3,fb2) MF(c33,fa3,fb3)

#define MMD \
    MF(d00,fa0,fb0) MF(d01,fa0,fb1) MF(d02,fa0,fb2) MF(d03,fa0,fb3) \
    MF(d10,fa1,fb0) MF(d11,fa1,fb1) MF(d12,fa1,fb2) MF(d13,fa1,fb3) \
    MF(d20,fa2,fb0) MF(d21,fa2,fb1) MF(d22,fa2,fb2) MF(d23,fa2,fb3) \
    MF(d30,fa3,fb0) MF(d31,fa3,fb1) MF(d32,fa3,fb2) MF(d33,fa3,fb3)

#define KSTEP(SO_) { \
    RDA(SO_) \
    { RDB(Bs0, SO_) MMC } \
    { RDB(Bs1, SO_) MMD } }

  for (int k0 = 0; k0 < 512; k0 += 64) {
    STG8(pa0, pa1, pa2, pa3, k0, As)
    STG8(pb0, pb1, pb2, pb3, k0, Bs0)
    STG8(pq0, pq1, pq2, pq3, k0, Bs1)
    __syncthreads();
    KSTEP(so0)
    KSTEP(so1)
    __syncthreads();
  }
  for (int k0 = 0; k0 < 512; k0 += 64) {
    STG8(ph0, ph1, ph2, ph3, k0, As)
    STG8(pb0, pb1, pb2, pb3, 512 + k0, Bs0)
    STG8(pq0, pq1, pq2, pq3, 512 + k0, Bs1)
    __syncthreads();
    KSTEP(so0)
    KSTEP(so1)
    __syncthreads();
  }
#undef KSTEP
#undef MMD
#undef MMC
#undef RDB
#undef RDA
#undef STG8

  if (isig) {
#define EPI(cmn, dmn, m_, n_) { \
    const int col = n0 + wc * 64 + n_ * 16 + fr; \
    const float bvi = biv[col], bvc = bcv[col]; \
    const int rbase = wr * 64 + m_ * 16 + fq * 4; \
    _Pragma("unroll") for (int j = 0; j < 4; ++j) { \
      const float iv = 1.f / (1.f + __expf(-(cmn[j] + bvi))); \
      const float gv = 2.f / (1.f + __expf(-2.f * (dmn[j] + bvc))) - 1.f; \
      G2[(size_t)(r0c + rbase + j) * 1024 + col] = f2h(iv * gv); } }
    EPI(c00, d00, 0, 0) EPI(c01, d01, 0, 1) EPI(c02, d02, 0, 2) EPI(c03, d03, 0, 3)
    EPI(c10, d10, 1, 0) EPI(c11, d11, 1, 1) EPI(c12, d12, 1, 2) EPI(c13, d13, 1, 3)
    EPI(c20, d20, 2, 0) EPI(c21, d21, 2, 1) EPI(c22, d22, 2, 2) EPI(c23, d23, 2, 3)
    EPI(c30, d30, 3, 0) EPI(c31, d31, 3, 1) EPI(c32, d32, 3, 2) EPI(c33, d33, 3, 3)
#undef EPI
  } else {
#define EPIF(cmn, m_, n_, COFF) { \
    const int col = fb * 256 + (COFF) + wc * 64 + n_ * 16 + fr; \
    const float bv = bfv[col]; \
    const int rbase = wr * 64 + m_ * 16 + fq * 4; \
    _Pragma("unroll") for (int j = 0; j < 4; ++j) { \
      const float fv = 1.f / (1.f + __expf(-(cmn[j] + bv))); \
      G2[(size_t)(r0c + rbase + j) * 1024 + 512 + col] = f2h(fv); } }
    EPIF(c00, 0, 0, 0) EPIF(c01, 0, 1, 0) EPIF(c02, 0, 2, 0) EPIF(c03, 0, 3, 0)
    EPIF(c10, 1, 0, 0) EPIF(c11, 1, 1, 0) EPIF(c12, 1, 2, 0) EPIF(c13, 1, 3, 0)
    EPIF(c20, 2, 0, 0) EPIF(c21, 2, 1, 0) EPIF(c22, 2, 2, 0) EPIF(c23, 2, 3, 0)
    EPIF(c30, 3, 0, 0) EPIF(c31, 3, 1, 0) EPIF(c32, 3, 2, 0) EPIF(c33, 3, 3, 0)
    EPIF(d00, 0, 0, 128) EPIF(d01, 0, 1, 128) EPIF(d02, 0, 2, 128) EPIF(d03, 0, 3, 128)
    EPIF(d10, 1, 0, 128) EPIF(d11, 1, 1, 128) EPIF(d12, 1, 2, 128) EPIF(d13, 1, 3, 128)
    EPIF(d20, 2, 0, 128) EPIF(d21, 2, 1, 128) EPIF(d22, 2, 2, 128) EPIF(d23, 2, 3, 128)
    EPIF(d30, 3, 0, 128) EPIF(d31, 3, 1, 128) EPIF(d32, 3, 2, 128) EPIF(d33, 3, 3, 128)
#undef EPIF
  }
}

// ------------------------------------------------ scan phase A
__global__ __launch_bounds__(256) void k3a_seg(
    const ushort* __restrict__ G2, float* __restrict__ Aseg,
    float* __restrict__ Bseg, int Tc)
{
  const int l = blockIdx.x * 256 + threadIdx.x;
  const int b = blockIdx.y, s = blockIdx.z;
  const int SEGc = Tc >> 6;
  const ushort* gb = G2 + ((size_t)(b * Tc + s * 64)) * 1024 + l;
  float A = 1.f, c = 0.f;
#pragma unroll 8
  for (int j = 0; j < 64; ++j) {
    const float P = h2f(gb[(size_t)j * 1024]);
    const float F = h2f(gb[(size_t)j * 1024 + 512]);
    A *= F;
    c = fmaf(F, c, P);
  }
  const size_t o = (size_t)(b * SEGc + s) * 512 + l;
  Aseg[o] = A;
  Bseg[o] = c;
}

// ------------------------------------------------ scan phase B
__global__ __launch_bounds__(512) void k3b_comb(
    const float* __restrict__ Aseg, const float* __restrict__ Bseg,
    const float* __restrict__ initc, float* __restrict__ cstart,
    float* __restrict__ cbuf, int tc, int Tc)
{
  const int b = blockIdx.x, l = threadIdx.x;
  const int SEGc = Tc >> 6;
  float c = (tc == 0) ? initc[l] : cbuf[b * 512 + l];
  for (int s = 0; s < SEGc; ++s) {
    const size_t o = (size_t)(b * SEGc + s) * 512 + l;
    cstart[o] = c;
    c = fmaf(Aseg[o], c, Bseg[o]);
  }
  cbuf[b * 512 + l] = c;
}

// ------------------------------------------------ scan phase C
__global__ __launch_bounds__(128) void k3c_emit(
    const ushort* __restrict__ G2, const ushort* __restrict__ Z,
    const float* __restrict__ cstart, float* __restrict__ out,
    int tc, int Tc)
{
  __shared__ float tile[128][65];
  const int tid = threadIdx.x;
  const int l0 = blockIdx.x * 128;
  const int b = blockIdx.y, s = blockIdx.z;
  const int SEGc = Tc >> 6;
  const int l = l0 + tid;

  float c = cstart[(size_t)(b * SEGc + s) * 512 + l];
  const ushort* gb = G2 + ((size_t)(b * Tc + s * 64)) * 1024 + l;
  const ushort* zb = Z + ((size_t)(b * 1024 + tc + s * 64)) * 512 + l;
#pragma unroll 8
  for (int j = 0; j < 64; ++j) {
    const float P = h2f(gb[(size_t)j * 1024]);
    const float F = h2f(gb[(size_t)j * 1024 + 512]);
    const float zv = bf2f(zb[(size_t)j * 512]);
    c = fmaf(F, c, P);
    tile[tid][j] = sinf(zv) * c;
  }
  __syncthreads();
  const int col = tid & 63, rhalf = tid >> 6;
  const size_t obase = ((size_t)b * 512 + l0) * 1024 + (size_t)(tc + s * 64) + col;
#pragma unroll
  for (int p = 0; p < 64; ++p) {
    const int row = rhalf + p * 2;
    out[obase + (size_t)row * 1024] = tile[row][col];
  }
}

// ------------------------------------------------ launcher
extern "C" void kernel_launch(void* const* d_in, const int* in_sizes, int n_in,
                              void* d_out, int out_size, void* d_ws, size_t ws_size,
                              hipStream_t stream)
{
  const float* x  = (const float*)d_in[0];
  const float* W  = (const float*)d_in[1];
  const float* rb = (const float*)d_in[2];
  const float* wi = (const float*)d_in[3];
  const float* wf = (const float*)d_in[4];
  const float* wc = (const float*)d_in[5];
  const float* ri = (const float*)d_in[6];
  const float* rf = (const float*)d_in[7];
  const float* rc = (const float*)d_in[8];
  const float* bi = (const float*)d_in[9];
  const float* bfo = (const float*)d_in[10];
  const float* bc = (const float*)d_in[11];
  const float* il = (const float*)d_in[12];
  const float* ic = (const float*)d_in[13];
  float* out = (float*)d_out;

  char* ws = (char*)d_ws;
  size_t off = 0;
  auto alloc = [&](size_t bytes) -> void* {
    void* p = ws + off;
    off = (off + bytes + 255) & ~(size_t)255;
    return p;
  };
  ushort* z    = (ushort*)alloc((size_t)65536 * 512 * 2);   // 67.1 MB
  ushort* W1t  = (ushort*)alloc((size_t)512 * 512 * 2);
  ushort* W2t  = (ushort*)alloc((size_t)1536 * 1024 * 2);
  ushort* ilb  = (ushort*)alloc(512 * 2);
  float*  cbuf = (float*)alloc((size_t)64 * 512 * 4);
  float*  Aseg = (float*)alloc((size_t)64 * 16 * 512 * 4);  // 2 MB
  float*  Bseg = (float*)alloc((size_t)64 * 16 * 512 * 4);
  float*  cstart = (float*)alloc((size_t)64 * 16 * 512 * 4);
  const size_t fixed_end = off;
  ushort* xt   = (ushort*)alloc((size_t)65536 * 512 * 2);   // dead after K1
  ushort* G2   = (ushort*)(ws + fixed_end);                 // aliases xt region

  int Tc = 1024;
  while (Tc > 128 && fixed_end + (size_t)64 * Tc * 1024 * 2 > ws_size) Tc >>= 1;

  // prep
  transpose8<<<dim3(16, 16, 8), 256, 0, stream>>>(
      wi, ri, wf, rf, wc, rc, il, W, W2t, ilb, W1t);
  transpose_x<<<dim3(16, 8, 64), 256, 0, stream>>>(x, xt);

  k1_mfma<<<dim3(1024), 256, 0, stream>>>(xt, W1t, rb, z);

  for (int tc = 0; tc < 1024; tc += Tc) {
    const int SEGc = Tc >> 6;
    const int nwg2 = 6 * 64 * (Tc >> 7);
    k2_mfma<<<dim3(nwg2), 256, 0, stream>>>(
        z, W2t, ilb, bi, bfo, bc, G2, tc, Tc, nwg2);
    k3a_seg<<<dim3(2, 64, SEGc), 256, 0, stream>>>(G2, Aseg, Bseg, Tc);
    k3b_comb<<<64, 512, 0, stream>>>(Aseg, Bseg, ic, cstart, cbuf, tc, Tc);
    k3c_emit<<<dim3(4, 64, SEGc), 128, 0, stream>>>(G2, z, cstart, out, tc, Tc);
  }
}

// Round 15
// 532.880 us; speedup vs baseline: 1.1946x; 1.1946x over previous
//
#include <hip/hip_runtime.h>
#include <hip/hip_bf16.h>
#include <hip/hip_fp16.h>
#include <cstdint>
#include <cstddef>

// B=64, D=512, T=1024, L=512
// prep_all: weights/il transpose (z<8) + x transpose (z>=8), one launch
// K1:    u = cos(xt @ rff_w + b)   (r12-proven 128x128 BK=64 swizzled)
// LN:    z = layernorm(u)          (r12-proven)
// K2:    uniform 6-block decomposition per 128-row tile (r12-proven)
// scan:  k3a summaries (vectorized) -> k3c (fused combine + emit + transpose)
//
// LESSONS: (r4-r6) acc arrays are NOT SROA-promoted -> scratch RMW; NAMED accs.
// (r8) XOR swizzle both-sides -> bank conflicts 2.5e7 -> 0. (r9 FAIL) loads
// across raw s_barriers race. (r10 FAIL) dbuf halved blocks/CU. (r14 FAIL)
// fused-LN BM=64xBN=512 shape is staging-issue-bound (16 gload/thread/step,
// 2 blocks/CU) -> +180us. Split k1+ln is structurally right.

typedef float f32x4 __attribute__((ext_vector_type(4)));
typedef short s16x8 __attribute__((ext_vector_type(8)));

__device__ __forceinline__ void gload_lds16(const void* g, void* l) {
  __builtin_amdgcn_global_load_lds(
      (const __attribute__((address_space(1))) void*)g,
      (__attribute__((address_space(3))) void*)l, 16, 0, 0);
}
__device__ __forceinline__ ushort f2bf(float f) {
  uint32_t u = __float_as_uint(f);
  return (ushort)((u + 0x7FFF + ((u >> 16) & 1)) >> 16);  // RNE
}
__device__ __forceinline__ float bf2f(ushort s) {
  return __uint_as_float(((uint32_t)s) << 16);
}
__device__ __forceinline__ ushort f2h(float f) {
  return __half_as_ushort(__float2half(f));
}
__device__ __forceinline__ float h2f(ushort s) {
  return __half2float(__ushort_as_half(s));
}

#define MF(d, a, b) d = __builtin_amdgcn_mfma_f32_16x16x32_bf16(a, b, d, 0, 0, 0);

// ------------------------------------------------ prep: everything in one launch
// z<6: gate weight transpose; z==6: il cvt; z==7: W1 transpose; z>=8: x transpose
__global__ __launch_bounds__(256) void prep_all(
    const float* __restrict__ s0, const float* __restrict__ s1,
    const float* __restrict__ s2, const float* __restrict__ s3,
    const float* __restrict__ s4, const float* __restrict__ s5,
    const float* __restrict__ il, const float* __restrict__ W1,
    const float* __restrict__ x,
    ushort* __restrict__ W2t, ushort* __restrict__ ilb,
    ushort* __restrict__ W1t, ushort* __restrict__ xt)
{
  __shared__ float tile[64][68];   // x-path uses all; weight path uses a corner
  const int z = blockIdx.z;
  if (z >= 8) {
    if (blockIdx.y >= 8) return;
    const int b = z - 8;
    const int t0 = blockIdx.x * 64, d0 = blockIdx.y * 64;
    const float* src = x + ((size_t)b * 512 + d0) * 1024 + t0;
    const int lr_ = threadIdx.x >> 4, lc4 = (threadIdx.x & 15) * 4;
#pragma unroll
    for (int p = 0; p < 4; ++p) {
      const float4 v = *(const float4*)(src + (size_t)(lr_ + p * 16) * 1024 + lc4);
      *(float4*)&tile[lr_ + p * 16][lc4] = v;
    }
    __syncthreads();
    const int tt = threadIdx.x >> 2, dc = (threadIdx.x & 3) * 16;
    ushort* dst = xt + ((size_t)b * 1024 + t0 + tt) * 512 + d0 + dc;
    uint4 o1, o2;
    o1.x = (uint)f2bf(tile[dc + 0][tt]) | ((uint)f2bf(tile[dc + 1][tt]) << 16);
    o1.y = (uint)f2bf(tile[dc + 2][tt]) | ((uint)f2bf(tile[dc + 3][tt]) << 16);
    o1.z = (uint)f2bf(tile[dc + 4][tt]) | ((uint)f2bf(tile[dc + 5][tt]) << 16);
    o1.w = (uint)f2bf(tile[dc + 6][tt]) | ((uint)f2bf(tile[dc + 7][tt]) << 16);
    o2.x = (uint)f2bf(tile[dc + 8][tt]) | ((uint)f2bf(tile[dc + 9][tt]) << 16);
    o2.y = (uint)f2bf(tile[dc + 10][tt]) | ((uint)f2bf(tile[dc + 11][tt]) << 16);
    o2.z = (uint)f2bf(tile[dc + 12][tt]) | ((uint)f2bf(tile[dc + 13][tt]) << 16);
    o2.w = (uint)f2bf(tile[dc + 14][tt]) | ((uint)f2bf(tile[dc + 15][tt]) << 16);
    *(uint4*)(dst) = o1;
    *(uint4*)(dst + 8) = o2;
    return;
  }
  if (z == 6) {
    if (blockIdx.x == 0 && blockIdx.y == 0) {
      ilb[threadIdx.x] = f2bf(il[threadIdx.x]);
      ilb[threadIdx.x + 256] = f2bf(il[threadIdx.x + 256]);
    }
    return;
  }
  const float* src = z == 0 ? s0 : z == 1 ? s1 : z == 2 ? s2
                   : z == 3 ? s3 : z == 4 ? s4 : z == 5 ? s5 : W1;
  ushort* dst = (z == 7) ? W1t
              : W2t + (size_t)(z >> 1) * 512 * 1024 + (z & 1) * 512;
  const int ld = (z == 7) ? 512 : 1024;
  float (*t32)[33] = (float(*)[33])&tile[0][0];
  const int c0 = blockIdx.x * 32, r0 = blockIdx.y * 32;
  const int tx = threadIdx.x & 31, ty = threadIdx.x >> 5;
#pragma unroll
  for (int i = 0; i < 4; ++i)
    t32[ty + i * 8][tx] = src[(size_t)(r0 + ty + i * 8) * 512 + c0 + tx];
  __syncthreads();
#pragma unroll
  for (int i = 0; i < 4; ++i)
    dst[(size_t)(c0 + ty + i * 8) * ld + r0 + tx] = f2bf(t32[tx][ty + i * 8]);
}

// ------------------------------------------------ K1 (r12-proven, unchanged)
__global__ __launch_bounds__(256, 2) void k1_mfma(
    const ushort* __restrict__ A, const ushort* __restrict__ Bt,
    const float* __restrict__ bias, ushort* __restrict__ U)
{
  __shared__ __align__(16) short As[128 * 64];
  __shared__ __align__(16) short Bs[128 * 64];
  const int tid = threadIdx.x;
  const int lane = tid & 63, wid = tid >> 6;
  const int orig = blockIdx.x;
  const int swz = (orig & 7) * 256 + (orig >> 3);
  const int n0 = (swz & 3) * 128, r0 = (swz >> 2) * 128;
  const int wr = wid >> 1, wc = wid & 1;
  const int fr = lane & 15, fq = lane >> 4;
  const int lr = lane >> 3;
  const int swz_el = ((lane & 7) ^ lr) * 8;

  const int RA = r0 + wid * 32 + lr;
  const ushort* pa0 = A + (size_t)(RA)      * 512 + swz_el;
  const ushort* pa1 = A + (size_t)(RA + 8)  * 512 + swz_el;
  const ushort* pa2 = A + (size_t)(RA + 16) * 512 + swz_el;
  const ushort* pa3 = A + (size_t)(RA + 24) * 512 + swz_el;
  const int RB = n0 + wid * 32 + lr;
  const ushort* pb0 = Bt + (size_t)(RB)      * 512 + swz_el;
  const ushort* pb1 = Bt + (size_t)(RB + 8)  * 512 + swz_el;
  const ushort* pb2 = Bt + (size_t)(RB + 16) * 512 + swz_el;
  const ushort* pb3 = Bt + (size_t)(RB + 24) * 512 + swz_el;
  char* dA = (char*)As + wid * 4096;
  char* dB = (char*)Bs + wid * 4096;

  const int so0 = fr * 64 + ((fq)     ^ (fr & 7)) * 8;
  const int so1 = fr * 64 + ((4 + fq) ^ (fr & 7)) * 8;

  f32x4 c00 = {0.f,0.f,0.f,0.f}, c01 = c00, c02 = c00, c03 = c00,
        c10 = c00, c11 = c00, c12 = c00, c13 = c00,
        c20 = c00, c21 = c00, c22 = c00, c23 = c00,
        c30 = c00, c31 = c00, c32 = c00, c33 = c00;

  for (int k0 = 0; k0 < 512; k0 += 64) {
    gload_lds16(pa0 + k0, dA);        gload_lds16(pa1 + k0, dA + 1024);
    gload_lds16(pa2 + k0, dA + 2048); gload_lds16(pa3 + k0, dA + 3072);
    gload_lds16(pb0 + k0, dB);        gload_lds16(pb1 + k0, dB + 1024);
    gload_lds16(pb2 + k0, dB + 2048); gload_lds16(pb3 + k0, dB + 3072);
    __syncthreads();
    const s16x8 a00 = *(const s16x8*)&As[wr * 4096 + 0 * 1024 + so0];
    const s16x8 a01 = *(const s16x8*)&As[wr * 4096 + 0 * 1024 + so1];
    const s16x8 a10 = *(const s16x8*)&As[wr * 4096 + 1 * 1024 + so0];
    const s16x8 a11 = *(const s16x8*)&As[wr * 4096 + 1 * 1024 + so1];
    const s16x8 a20 = *(const s16x8*)&As[wr * 4096 + 2 * 1024 + so0];
    const s16x8 a21 = *(const s16x8*)&As[wr * 4096 + 2 * 1024 + so1];
    const s16x8 a30 = *(const s16x8*)&As[wr * 4096 + 3 * 1024 + so0];
    const s16x8 a31 = *(const s16x8*)&As[wr * 4096 + 3 * 1024 + so1];
    const s16x8 b00 = *(const s16x8*)&Bs[wc * 4096 + 0 * 1024 + so0];
    const s16x8 b01 = *(const s16x8*)&Bs[wc * 4096 + 0 * 1024 + so1];
    const s16x8 b10 = *(const s16x8*)&Bs[wc * 4096 + 1 * 1024 + so0];
    const s16x8 b11 = *(const s16x8*)&Bs[wc * 4096 + 1 * 1024 + so1];
    const s16x8 b20 = *(const s16x8*)&Bs[wc * 4096 + 2 * 1024 + so0];
    const s16x8 b21 = *(const s16x8*)&Bs[wc * 4096 + 2 * 1024 + so1];
    const s16x8 b30 = *(const s16x8*)&Bs[wc * 4096 + 3 * 1024 + so0];
    const s16x8 b31 = *(const s16x8*)&Bs[wc * 4096 + 3 * 1024 + so1];
    MF(c00, a00, b00) MF(c01, a00, b10) MF(c02, a00, b20) MF(c03, a00, b30)
    MF(c10, a10, b00) MF(c11, a10, b10) MF(c12, a10, b20) MF(c13, a10, b30)
    MF(c20, a20, b00) MF(c21, a20, b10) MF(c22, a20, b20) MF(c23, a20, b30)
    MF(c30, a30, b00) MF(c31, a30, b10) MF(c32, a30, b20) MF(c33, a30, b30)
    MF(c00, a01, b01) MF(c01, a01, b11) MF(c02, a01, b21) MF(c03, a01, b31)
    MF(c10, a11, b01) MF(c11, a11, b11) MF(c12, a11, b21) MF(c13, a11, b31)
    MF(c20, a21, b01) MF(c21, a21, b11) MF(c22, a21, b21) MF(c23, a21, b31)
    MF(c30, a31, b01) MF(c31, a31, b11) MF(c32, a31, b21) MF(c33, a31, b31)
    __syncthreads();
  }

#define EPI1(cmn, m_, n_) { \
    const int col = n0 + wc * 64 + n_ * 16 + fr; \
    const float bv = bias[col]; \
    const int rbase = r0 + wr * 64 + m_ * 16 + fq * 4; \
    _Pragma("unroll") for (int j = 0; j < 4; ++j) \
      U[(size_t)(rbase + j) * 512 + col] = f2bf(cosf(cmn[j] + bv)); }
  EPI1(c00, 0, 0) EPI1(c01, 0, 1) EPI1(c02, 0, 2) EPI1(c03, 0, 3)
  EPI1(c10, 1, 0) EPI1(c11, 1, 1) EPI1(c12, 1, 2) EPI1(c13, 1, 3)
  EPI1(c20, 2, 0) EPI1(c21, 2, 1) EPI1(c22, 2, 2) EPI1(c23, 2, 3)
  EPI1(c30, 3, 0) EPI1(c31, 3, 1) EPI1(c32, 3, 2) EPI1(c33, 3, 3)
#undef EPI1
}

// ------------------------------------------------ LN: one wave per 512-row
__global__ __launch_bounds__(256) void ln_rows(
    const ushort* __restrict__ U, ushort* __restrict__ Z)
{
  const int row = blockIdx.x * 4 + (threadIdx.x >> 6);
  const int lane = threadIdx.x & 63;
  const size_t base = (size_t)row * 512 + lane * 8;
  const uint4 pk = *(const uint4*)(U + base);
  float v[8];
  v[0] = bf2f(pk.x & 0xffff); v[1] = bf2f(pk.x >> 16);
  v[2] = bf2f(pk.y & 0xffff); v[3] = bf2f(pk.y >> 16);
  v[4] = bf2f(pk.z & 0xffff); v[5] = bf2f(pk.z >> 16);
  v[6] = bf2f(pk.w & 0xffff); v[7] = bf2f(pk.w >> 16);
  float s = 0.f, s2 = 0.f;
#pragma unroll
  for (int j = 0; j < 8; ++j) { s += v[j]; s2 += v[j] * v[j]; }
#pragma unroll
  for (int m = 1; m < 64; m <<= 1) { s += __shfl_xor(s, m); s2 += __shfl_xor(s2, m); }
  const float mean = s * (1.f / 512.f);
  const float var = s2 * (1.f / 512.f) - mean * mean;
  const float inv = rsqrtf(var + 1e-5f);
  uint4 o;
  o.x = (uint)f2bf((v[0] - mean) * inv) | ((uint)f2bf((v[1] - mean) * inv) << 16);
  o.y = (uint)f2bf((v[2] - mean) * inv) | ((uint)f2bf((v[3] - mean) * inv) << 16);
  o.z = (uint)f2bf((v[4] - mean) * inv) | ((uint)f2bf((v[5] - mean) * inv) << 16);
  o.w = (uint)f2bf((v[6] - mean) * inv) | ((uint)f2bf((v[7] - mean) * inv) << 16);
  *(uint4*)(Z + base) = o;
}

// ------------------------------------------------ K2 (r12-proven, unchanged)
__global__ __launch_bounds__(256, 2) void k2_mfma(
    const ushort* __restrict__ Z, const ushort* __restrict__ Wt,
    const ushort* __restrict__ IL,
    const float* __restrict__ biv, const float* __restrict__ bfv,
    const float* __restrict__ bcv,
    ushort* __restrict__ G2, int tc, int Tc, int nwg)
{
  __shared__ __align__(16) short As[128 * 64];
  __shared__ __align__(16) short Bs0[128 * 64];
  __shared__ __align__(16) short Bs1[128 * 64];
  const int tid = threadIdx.x;
  const int lane = tid & 63, wid = tid >> 6;
  const int cpx = nwg >> 3;
  const int orig = blockIdx.x;
  const int swz = (orig & 7) * cpx + (orig >> 3);
  const int bx = swz % 6, by = swz / 6;
  const int nb = Tc >> 7;
  const int b = by / nb, tb = by % nb;
  const int r0g = b * 1024 + tc + tb * 128;
  const int r0c = b * Tc + tb * 128;
  const bool isig = bx < 4;
  const int n0 = isig ? bx * 128 : 0;
  const int fb = bx - 4;
  const int wr = wid >> 1, wc = wid & 1;
  const int fr = lane & 15, fq = lane >> 4;
  const int lr = lane >> 3;
  const int swz_el = ((lane & 7) ^ lr) * 8;

  const int R0 = r0g + wid * 32 + lr;
  const ushort* pa0 = Z + (size_t)(R0)      * 512 + swz_el;
  const ushort* pa1 = Z + (size_t)(R0 + 8)  * 512 + swz_el;
  const ushort* pa2 = Z + (size_t)(R0 + 16) * 512 + swz_el;
  const ushort* pa3 = Z + (size_t)(R0 + 24) * 512 + swz_el;
  const ushort* ph0 = ((((R0)      & 1023) == 0) ? IL : (Z + (size_t)(R0 - 1)  * 512)) + swz_el;
  const ushort* ph1 = ((((R0 + 8)  & 1023) == 0) ? IL : (Z + (size_t)(R0 + 7)  * 512)) + swz_el;
  const ushort* ph2 = ((((R0 + 16) & 1023) == 0) ? IL : (Z + (size_t)(R0 + 15) * 512)) + swz_el;
  const ushort* ph3 = ((((R0 + 24) & 1023) == 0) ? IL : (Z + (size_t)(R0 + 23) * 512)) + swz_el;
  const int RB0 = (isig ? n0 : 512 + fb * 256) + wid * 32 + lr;
  const ushort* pb0 = Wt + (size_t)(RB0)      * 1024 + swz_el;
  const ushort* pb1 = Wt + (size_t)(RB0 + 8)  * 1024 + swz_el;
  const ushort* pb2 = Wt + (size_t)(RB0 + 16) * 1024 + swz_el;
  const ushort* pb3 = Wt + (size_t)(RB0 + 24) * 1024 + swz_el;
  const int RB1 = (isig ? 1024 + n0 : 512 + fb * 256 + 128) + wid * 32 + lr;
  const ushort* pq0 = Wt + (size_t)(RB1)      * 1024 + swz_el;
  const ushort* pq1 = Wt + (size_t)(RB1 + 8)  * 1024 + swz_el;
  const ushort* pq2 = Wt + (size_t)(RB1 + 16) * 1024 + swz_el;
  const ushort* pq3 = Wt + (size_t)(RB1 + 24) * 1024 + swz_el;

  const int so0 = fr * 64 + ((fq)     ^ (fr & 7)) * 8;
  const int so1 = fr * 64 + ((4 + fq) ^ (fr & 7)) * 8;

  f32x4 zz = {0.f,0.f,0.f,0.f};
  f32x4 c00=zz,c01=zz,c02=zz,c03=zz, c10=zz,c11=zz,c12=zz,c13=zz,
        c20=zz,c21=zz,c22=zz,c23=zz, c30=zz,c31=zz,c32=zz,c33=zz;
  f32x4 d00=zz,d01=zz,d02=zz,d03=zz, d10=zz,d11=zz,d12=zz,d13=zz,
        d20=zz,d21=zz,d22=zz,d23=zz, d30=zz,d31=zz,d32=zz,d33=zz;

#define STG8(P0,P1,P2,P3, KO, DST) { \
    char* d_ = (char*)(DST) + wid * 4096; \
    gload_lds16((P0) + (KO), d_);        gload_lds16((P1) + (KO), d_ + 1024); \
    gload_lds16((P2) + (KO), d_ + 2048); gload_lds16((P3) + (KO), d_ + 3072); }

#define RDA(SO) \
    const s16x8 fa0 = *(const s16x8*)&As[wr * 4096 + 0 * 1024 + (SO)]; \
    const s16x8 fa1 = *(const s16x8*)&As[wr * 4096 + 1 * 1024 + (SO)]; \
    const s16x8 fa2 = *(const s16x8*)&As[wr * 4096 + 2 * 1024 + (SO)]; \
    const s16x8 fa3 = *(const s16x8*)&As[wr * 4096 + 3 * 1024 + (SO)];

#define RDB(BS, SO) \
    const s16x8 fb0 = *(const s16x8*)&(BS)[wc * 4096 + 0 * 1024 + (SO)]; \
    const s16x8 fb1 = *(const s16x8*)&(BS)[wc * 4096 + 1 * 1024 + (SO)]; \
    const s16x8 fb2 = *(const s16x8*)&(BS)[wc * 4096 + 2 * 1024 + (SO)]; \
    const s16x8 fb3 = *(const s16x8*)&(BS)[wc * 4096 + 3 * 1024 + (SO)];

#define MMC \
    MF(c00,fa0,fb0) MF(c01,fa0,fb1) MF(c02,fa0,fb2) MF(c03,fa0,fb3) \
    MF(c10,fa1,fb0) MF(c11,fa1,fb1) MF(c12,fa1,fb2) MF(c13,fa1,fb3) \
    MF(c20,fa2,fb0) MF(c21,fa2,fb1) MF(c22,fa2,fb2) MF(c23,fa2,fb3) \
    MF(c30,fa3,fb0) MF(c31,fa3,fb1) MF(c32,fa3,fb2) MF(c33,fa3,fb3)

#define MMD \
    MF(d00,fa0,fb0) MF(d01,fa0,fb1) MF(d02,fa0,fb2) MF(d03,fa0,fb3) \
    MF(d10,fa1,fb0) MF(d11,fa1,fb1) MF(d12,fa1,fb2) MF(d13,fa1,fb3) \
    MF(d20,fa2,fb0) MF(d21,fa2,fb1) MF(d22,fa2,fb2) MF(d23,fa2,fb3) \
    MF(d30,fa3,fb0) MF(d31,fa3,fb1) MF(d32,fa3,fb2) MF(d33,fa3,fb3)

#define KSTEP(SO_) { \
    RDA(SO_) \
    { RDB(Bs0, SO_) MMC } \
    { RDB(Bs1, SO_) MMD } }

  for (int k0 = 0; k0 < 512; k0 += 64) {
    STG8(pa0, pa1, pa2, pa3, k0, As)
    STG8(pb0, pb1, pb2, pb3, k0, Bs0)
    STG8(pq0, pq1, pq2, pq3, k0, Bs1)
    __syncthreads();
    KSTEP(so0)
    KSTEP(so1)
    __syncthreads();
  }
  for (int k0 = 0; k0 < 512; k0 += 64) {
    STG8(ph0, ph1, ph2, ph3, k0, As)
    STG8(pb0, pb1, pb2, pb3, 512 + k0, Bs0)
    STG8(pq0, pq1, pq2, pq3, 512 + k0, Bs1)
    __syncthreads();
    KSTEP(so0)
    KSTEP(so1)
    __syncthreads();
  }
#undef KSTEP
#undef MMD
#undef MMC
#undef RDB
#undef RDA
#undef STG8

  if (isig) {
#define EPI(cmn, dmn, m_, n_) { \
    const int col = n0 + wc * 64 + n_ * 16 + fr; \
    const float bvi = biv[col], bvc = bcv[col]; \
    const int rbase = wr * 64 + m_ * 16 + fq * 4; \
    _Pragma("unroll") for (int j = 0; j < 4; ++j) { \
      const float iv = 1.f / (1.f + __expf(-(cmn[j] + bvi))); \
      const float gv = 2.f / (1.f + __expf(-2.f * (dmn[j] + bvc))) - 1.f; \
      G2[(size_t)(r0c + rbase + j) * 1024 + col] = f2h(iv * gv); } }
    EPI(c00, d00, 0, 0) EPI(c01, d01, 0, 1) EPI(c02, d02, 0, 2) EPI(c03, d03, 0, 3)
    EPI(c10, d10, 1, 0) EPI(c11, d11, 1, 1) EPI(c12, d12, 1, 2) EPI(c13, d13, 1, 3)
    EPI(c20, d20, 2, 0) EPI(c21, d21, 2, 1) EPI(c22, d22, 2, 2) EPI(c23, d23, 2, 3)
    EPI(c30, d30, 3, 0) EPI(c31, d31, 3, 1) EPI(c32, d32, 3, 2) EPI(c33, d33, 3, 3)
#undef EPI
  } else {
#define EPIF(cmn, m_, n_, COFF) { \
    const int col = fb * 256 + (COFF) + wc * 64 + n_ * 16 + fr; \
    const float bv = bfv[col]; \
    const int rbase = wr * 64 + m_ * 16 + fq * 4; \
    _Pragma("unroll") for (int j = 0; j < 4; ++j) { \
      const float fv = 1.f / (1.f + __expf(-(cmn[j] + bv))); \
      G2[(size_t)(r0c + rbase + j) * 1024 + 512 + col] = f2h(fv); } }
    EPIF(c00, 0, 0, 0) EPIF(c01, 0, 1, 0) EPIF(c02, 0, 2, 0) EPIF(c03, 0, 3, 0)
    EPIF(c10, 1, 0, 0) EPIF(c11, 1, 1, 0) EPIF(c12, 1, 2, 0) EPIF(c13, 1, 3, 0)
    EPIF(c20, 2, 0, 0) EPIF(c21, 2, 1, 0) EPIF(c22, 2, 2, 0) EPIF(c23, 2, 3, 0)
    EPIF(c30, 3, 0, 0) EPIF(c31, 3, 1, 0) EPIF(c32, 3, 2, 0) EPIF(c33, 3, 3, 0)
    EPIF(d00, 0, 0, 128) EPIF(d01, 0, 1, 128) EPIF(d02, 0, 2, 128) EPIF(d03, 0, 3, 128)
    EPIF(d10, 1, 0, 128) EPIF(d11, 1, 1, 128) EPIF(d12, 1, 2, 128) EPIF(d13, 1, 3, 128)
    EPIF(d20, 2, 0, 128) EPIF(d21, 2, 1, 128) EPIF(d22, 2, 2, 128) EPIF(d23, 2, 3, 128)
    EPIF(d30, 3, 0, 128) EPIF(d31, 3, 1, 128) EPIF(d32, 3, 2, 128) EPIF(d33, 3, 3, 128)
#undef EPIF
  }
}

// ------------------------------------------------ scan phase A (vectorized 2 l/thread)
__global__ __launch_bounds__(256) void k3a_seg(
    const ushort* __restrict__ G2, float* __restrict__ Aseg,
    float* __restrict__ Bseg, int Tc)
{
  const int l2 = threadIdx.x * 2;
  const int b = blockIdx.x, s = blockIdx.y;
  const int SEGc = Tc >> 6;
  const ushort* gb = G2 + ((size_t)(b * Tc + s * 64)) * 1024;
  float A0 = 1.f, A1 = 1.f, c0 = 0.f, c1 = 0.f;
#pragma unroll 8
  for (int j = 0; j < 64; ++j) {
    const uint Pp = *(const uint*)(gb + (size_t)j * 1024 + l2);
    const uint Fp = *(const uint*)(gb + (size_t)j * 1024 + 512 + l2);
    const float P0 = h2f((ushort)(Pp & 0xffff)), P1 = h2f((ushort)(Pp >> 16));
    const float F0 = h2f((ushort)(Fp & 0xffff)), F1 = h2f((ushort)(Fp >> 16));
    A0 *= F0; A1 *= F1;
    c0 = fmaf(F0, c0, P0); c1 = fmaf(F1, c1, P1);
  }
  const size_t o = (size_t)(b * SEGc + s) * 512 + l2;
  float2 av; av.x = A0; av.y = A1;
  float2 bv; bv.x = c0; bv.y = c1;
  *(float2*)(Aseg + o) = av;
  *(float2*)(Bseg + o) = bv;
}

// ------------------------------------------------ scan phase C (fused combine+emit)
__global__ __launch_bounds__(128) void k3c_emit(
    const ushort* __restrict__ G2, const ushort* __restrict__ Z,
    const float* __restrict__ Aseg, const float* __restrict__ Bseg,
    const float* __restrict__ initc, float* __restrict__ cbuf,
    float* __restrict__ out, int tc, int Tc)
{
  __shared__ float tile[128][65];
  const int tid = threadIdx.x;
  const int l0 = blockIdx.x * 128;
  const int b = blockIdx.y, s = blockIdx.z;
  const int SEGc = Tc >> 6;
  const int l = l0 + tid;

  // reconstruct segment-start c from per-segment summaries (replaces k3b).
  // Loads are unconditional (buffer fully allocated for sp<16); identity-
  // selected for sp >= s so the compiler can hoist all loads before the chain.
  float c = (tc == 0) ? initc[l] : cbuf[b * 512 + l];
#pragma unroll
  for (int sp = 0; sp < 15; ++sp) {
    const size_t o = (size_t)(b * SEGc + sp) * 512 + l;
    const float Av = Aseg[o], Bv = Bseg[o];
    c = (sp < s) ? fmaf(Av, c, Bv) : c;
  }

  const ushort* gb = G2 + ((size_t)(b * Tc + s * 64)) * 1024 + l;
  const ushort* zb = Z + ((size_t)(b * 1024 + tc + s * 64)) * 512 + l;
#pragma unroll 8
  for (int j = 0; j < 64; ++j) {
    const float P = h2f(gb[(size_t)j * 1024]);
    const float F = h2f(gb[(size_t)j * 1024 + 512]);
    const float zv = bf2f(zb[(size_t)j * 512]);
    c = fmaf(F, c, P);
    tile[tid][j] = sinf(zv) * c;
  }
  if (s == SEGc - 1) cbuf[b * 512 + l] = c;   // chunk carry (replaces k3b)
  __syncthreads();
  const int col = tid & 63, rhalf = tid >> 6;
  const size_t obase = ((size_t)b * 512 + l0) * 1024 + (size_t)(tc + s * 64) + col;
#pragma unroll
  for (int p = 0; p < 64; ++p) {
    const int row = rhalf + p * 2;
    out[obase + (size_t)row * 1024] = tile[row][col];
  }
}

// ------------------------------------------------ launcher
extern "C" void kernel_launch(void* const* d_in, const int* in_sizes, int n_in,
                              void* d_out, int out_size, void* d_ws, size_t ws_size,
                              hipStream_t stream)
{
  const float* x  = (const float*)d_in[0];
  const float* W  = (const float*)d_in[1];
  const float* rb = (const float*)d_in[2];
  const float* wi = (const float*)d_in[3];
  const float* wf = (const float*)d_in[4];
  const float* wc = (const float*)d_in[5];
  const float* ri = (const float*)d_in[6];
  const float* rf = (const float*)d_in[7];
  const float* rc = (const float*)d_in[8];
  const float* bi = (const float*)d_in[9];
  const float* bfo = (const float*)d_in[10];
  const float* bc = (const float*)d_in[11];
  const float* il = (const float*)d_in[12];
  const float* ic = (const float*)d_in[13];
  float* out = (float*)d_out;

  char* ws = (char*)d_ws;
  size_t off = 0;
  auto alloc = [&](size_t bytes) -> void* {
    void* p = ws + off;
    off = (off + bytes + 255) & ~(size_t)255;
    return p;
  };
  ushort* z    = (ushort*)alloc((size_t)65536 * 512 * 2);   // 67.1 MB
  ushort* W1t  = (ushort*)alloc((size_t)512 * 512 * 2);
  ushort* W2t  = (ushort*)alloc((size_t)1536 * 1024 * 2);
  ushort* ilb  = (ushort*)alloc(512 * 2);
  float*  cbuf = (float*)alloc((size_t)64 * 512 * 4);
  float*  Aseg = (float*)alloc((size_t)64 * 16 * 512 * 4);  // 2 MB
  float*  Bseg = (float*)alloc((size_t)64 * 16 * 512 * 4);
  const size_t fixed_end = off;
  ushort* xt   = (ushort*)alloc((size_t)65536 * 512 * 2);   // dead after K1
  ushort* G2   = (ushort*)(ws + fixed_end);                 // aliases xt region
  ushort* u    = (ushort*)d_out;                            // dead before k3c

  int Tc = 1024;
  while (Tc > 128 && fixed_end + (size_t)64 * Tc * 1024 * 2 > ws_size) Tc >>= 1;

  // prep (single launch: weights z<8, x-transpose z>=8)
  prep_all<<<dim3(16, 16, 72), 256, 0, stream>>>(
      wi, ri, wf, rf, wc, rc, il, W, x, W2t, ilb, W1t, xt);

  k1_mfma<<<dim3(2048), 256, 0, stream>>>(xt, W1t, rb, u);
  ln_rows<<<16384, 256, 0, stream>>>(u, z);

  for (int tc = 0; tc < 1024; tc += Tc) {
    const int SEGc = Tc >> 6;
    const int nwg2 = 6 * 64 * (Tc >> 7);
    k2_mfma<<<dim3(nwg2), 256, 0, stream>>>(
        z, W2t, ilb, bi, bfo, bc, G2, tc, Tc, nwg2);
    k3a_seg<<<dim3(64, SEGc), 256, 0, stream>>>(G2, Aseg, Bseg, Tc);
    k3c_emit<<<dim3(4, 64, SEGc), 128, 0, stream>>>(
        G2, z, Aseg, Bseg, ic, cbuf, out, tc, Tc);
  }
}

// Round 16
// 509.950 us; speedup vs baseline: 1.2483x; 1.0450x over previous
//
#include <hip/hip_runtime.h>
#include <hip/hip_bf16.h>
#include <hip/hip_fp16.h>
#include <cstdint>
#include <cstddef>

// B=64, D=512, T=1024, L=512
// prep_all: weight transposes + il (weights only now)
// K1:    u = cos(x @ rff_w + b)  — A-operand read DIRECTLY from x fp32 with
//        in-kernel LDS transpose (kills the 268 MB xt round-trip)
// LN:    z = layernorm(u)
// K2:    uniform 6-block decomposition per 128-row tile (r12-proven)
// scan:  k3a summaries (vectorized) -> k3c (fused combine + emit + transpose)
//
// LESSONS: (r4-r6) acc arrays are NOT SROA-promoted -> NAMED accs. (r8) XOR
// swizzle both-sides -> bank conflicts 0. (r9 FAIL) loads across raw
// s_barriers race. (r10 FAIL) dbuf halved blocks/CU. (r14 FAIL) BM=64xBN=512
// fused-LN shape is staging-bound. (r16) A-tile of k1 is row-contiguous in x
// -> reg-staged transpose replaces the separate transpose kernel.

typedef float f32x4 __attribute__((ext_vector_type(4)));
typedef short s16x8 __attribute__((ext_vector_type(8)));

__device__ __forceinline__ void gload_lds16(const void* g, void* l) {
  __builtin_amdgcn_global_load_lds(
      (const __attribute__((address_space(1))) void*)g,
      (__attribute__((address_space(3))) void*)l, 16, 0, 0);
}
__device__ __forceinline__ ushort f2bf(float f) {
  uint32_t u = __float_as_uint(f);
  return (ushort)((u + 0x7FFF + ((u >> 16) & 1)) >> 16);  // RNE
}
__device__ __forceinline__ float bf2f(ushort s) {
  return __uint_as_float(((uint32_t)s) << 16);
}
__device__ __forceinline__ ushort f2h(float f) {
  return __half_as_ushort(__float2half(f));
}
__device__ __forceinline__ float h2f(ushort s) {
  return __half2float(__ushort_as_half(s));
}

#define MF(d, a, b) d = __builtin_amdgcn_mfma_f32_16x16x32_bf16(a, b, d, 0, 0, 0);

// ------------------------------------------------ prep: 6 gate weights + W1 + il
__global__ __launch_bounds__(256) void prep_all(
    const float* __restrict__ s0, const float* __restrict__ s1,
    const float* __restrict__ s2, const float* __restrict__ s3,
    const float* __restrict__ s4, const float* __restrict__ s5,
    const float* __restrict__ il, const float* __restrict__ W1,
    ushort* __restrict__ W2t, ushort* __restrict__ ilb,
    ushort* __restrict__ W1t)
{
  __shared__ float tile[32][33];
  const int z = blockIdx.z;
  if (z == 6) {
    if (blockIdx.x == 0 && blockIdx.y == 0) {
      ilb[threadIdx.x] = f2bf(il[threadIdx.x]);
      ilb[threadIdx.x + 256] = f2bf(il[threadIdx.x + 256]);
    }
    return;
  }
  const float* src = z == 0 ? s0 : z == 1 ? s1 : z == 2 ? s2
                   : z == 3 ? s3 : z == 4 ? s4 : z == 5 ? s5 : W1;
  ushort* dst = (z == 7) ? W1t
              : W2t + (size_t)(z >> 1) * 512 * 1024 + (z & 1) * 512;
  const int ld = (z == 7) ? 512 : 1024;
  const int c0 = blockIdx.x * 32, r0 = blockIdx.y * 32;
  const int tx = threadIdx.x & 31, ty = threadIdx.x >> 5;
#pragma unroll
  for (int i = 0; i < 4; ++i)
    tile[ty + i * 8][tx] = src[(size_t)(r0 + ty + i * 8) * 512 + c0 + tx];
  __syncthreads();
#pragma unroll
  for (int i = 0; i < 4; ++i)
    dst[(size_t)(c0 + ty + i * 8) * ld + r0 + tx] = f2bf(tile[tx][ty + i * 8]);
}

// ------------------------------------------------ K1: u = cos(x @ W1t^T + b)
// A staged from x fp32 [b][d][t] directly: per K-step, thread loads 4 chunks
// of 8 d-values (lane-coalesced over t) and ds_writes swizzled bf16x8.
__global__ __launch_bounds__(256, 2) void k1_mfma(
    const float* __restrict__ x, const ushort* __restrict__ Bt,
    const float* __restrict__ bias, ushort* __restrict__ U)
{
  __shared__ __align__(16) short As[128 * 64];
  __shared__ __align__(16) short Bs[128 * 64];
  const int tid = threadIdx.x;
  const int lane = tid & 63, wid = tid >> 6;
  const int orig = blockIdx.x;
  const int swz = (orig & 7) * 256 + (orig >> 3);
  const int n0 = (swz & 3) * 128, r0 = (swz >> 2) * 128;
  const int b = r0 >> 10, t0 = r0 & 1023;   // 128 | 1024 -> one b per block
  const int wr = wid >> 1, wc = wid & 1;
  const int fr = lane & 15, fq = lane >> 4;
  const int lr = lane >> 3;
  const int swz_el = ((lane & 7) ^ lr) * 8;

  // A source: x[b][d][t0 + tA], lane-coalesced over tA
  const float* xb = x + ((size_t)b * 512) * 1024 + t0;
  const int tA = tid & 127, hA = tid >> 7;

  const int RB = n0 + wid * 32 + lr;
  const ushort* pb0 = Bt + (size_t)(RB)      * 512 + swz_el;
  const ushort* pb1 = Bt + (size_t)(RB + 8)  * 512 + swz_el;
  const ushort* pb2 = Bt + (size_t)(RB + 16) * 512 + swz_el;
  const ushort* pb3 = Bt + (size_t)(RB + 24) * 512 + swz_el;
  char* dB = (char*)Bs + wid * 4096;

  const int so0 = fr * 64 + ((fq)     ^ (fr & 7)) * 8;
  const int so1 = fr * 64 + ((4 + fq) ^ (fr & 7)) * 8;

  f32x4 c00 = {0.f,0.f,0.f,0.f}, c01 = c00, c02 = c00, c03 = c00,
        c10 = c00, c11 = c00, c12 = c00, c13 = c00,
        c20 = c00, c21 = c00, c22 = c00, c23 = c00,
        c30 = c00, c31 = c00, c32 = c00, c33 = c00;

  for (int k0 = 0; k0 < 512; k0 += 64) {
    // B staging (async, flies under A reg-staging)
    gload_lds16(pb0 + k0, dB);        gload_lds16(pb1 + k0, dB + 1024);
    gload_lds16(pb2 + k0, dB + 2048); gload_lds16(pb3 + k0, dB + 3072);
    // A staging: 4 chunks of 8 d-values each, transposed + swizzled
#pragma unroll
    for (int q = 0; q < 4; ++q) {
      const int c = hA * 4 + q;
      const float* src = xb + (size_t)(k0 + c * 8) * 1024 + tA;
      const float v0 = src[0 * 1024], v1 = src[1 * 1024];
      const float v2 = src[2 * 1024], v3 = src[3 * 1024];
      const float v4 = src[4 * 1024], v5 = src[5 * 1024];
      const float v6 = src[6 * 1024], v7 = src[7 * 1024];
      uint4 o;
      o.x = (uint)f2bf(v0) | ((uint)f2bf(v1) << 16);
      o.y = (uint)f2bf(v2) | ((uint)f2bf(v3) << 16);
      o.z = (uint)f2bf(v4) | ((uint)f2bf(v5) << 16);
      o.w = (uint)f2bf(v6) | ((uint)f2bf(v7) << 16);
      *(uint4*)&As[tA * 64 + ((c ^ (tA & 7)) * 8)] = o;
    }
    __syncthreads();
    const s16x8 a00 = *(const s16x8*)&As[wr * 4096 + 0 * 1024 + so0];
    const s16x8 a01 = *(const s16x8*)&As[wr * 4096 + 0 * 1024 + so1];
    const s16x8 a10 = *(const s16x8*)&As[wr * 4096 + 1 * 1024 + so0];
    const s16x8 a11 = *(const s16x8*)&As[wr * 4096 + 1 * 1024 + so1];
    const s16x8 a20 = *(const s16x8*)&As[wr * 4096 + 2 * 1024 + so0];
    const s16x8 a21 = *(const s16x8*)&As[wr * 4096 + 2 * 1024 + so1];
    const s16x8 a30 = *(const s16x8*)&As[wr * 4096 + 3 * 1024 + so0];
    const s16x8 a31 = *(const s16x8*)&As[wr * 4096 + 3 * 1024 + so1];
    const s16x8 b00 = *(const s16x8*)&Bs[wc * 4096 + 0 * 1024 + so0];
    const s16x8 b01 = *(const s16x8*)&Bs[wc * 4096 + 0 * 1024 + so1];
    const s16x8 b10 = *(const s16x8*)&Bs[wc * 4096 + 1 * 1024 + so0];
    const s16x8 b11 = *(const s16x8*)&Bs[wc * 4096 + 1 * 1024 + so1];
    const s16x8 b20 = *(const s16x8*)&Bs[wc * 4096 + 2 * 1024 + so0];
    const s16x8 b21 = *(const s16x8*)&Bs[wc * 4096 + 2 * 1024 + so1];
    const s16x8 b30 = *(const s16x8*)&Bs[wc * 4096 + 3 * 1024 + so0];
    const s16x8 b31 = *(const s16x8*)&Bs[wc * 4096 + 3 * 1024 + so1];
    MF(c00, a00, b00) MF(c01, a00, b10) MF(c02, a00, b20) MF(c03, a00, b30)
    MF(c10, a10, b00) MF(c11, a10, b10) MF(c12, a10, b20) MF(c13, a10, b30)
    MF(c20, a20, b00) MF(c21, a20, b10) MF(c22, a20, b20) MF(c23, a20, b30)
    MF(c30, a30, b00) MF(c31, a30, b10) MF(c32, a30, b20) MF(c33, a30, b30)
    MF(c00, a01, b01) MF(c01, a01, b11) MF(c02, a01, b21) MF(c03, a01, b31)
    MF(c10, a11, b01) MF(c11, a11, b11) MF(c12, a11, b21) MF(c13, a11, b31)
    MF(c20, a21, b01) MF(c21, a21, b11) MF(c22, a21, b21) MF(c23, a21, b31)
    MF(c30, a31, b01) MF(c31, a31, b11) MF(c32, a31, b21) MF(c33, a31, b31)
    __syncthreads();
  }

#define EPI1(cmn, m_, n_) { \
    const int col = n0 + wc * 64 + n_ * 16 + fr; \
    const float bv = bias[col]; \
    const int rbase = r0 + wr * 64 + m_ * 16 + fq * 4; \
    _Pragma("unroll") for (int j = 0; j < 4; ++j) \
      U[(size_t)(rbase + j) * 512 + col] = f2bf(cosf(cmn[j] + bv)); }
  EPI1(c00, 0, 0) EPI1(c01, 0, 1) EPI1(c02, 0, 2) EPI1(c03, 0, 3)
  EPI1(c10, 1, 0) EPI1(c11, 1, 1) EPI1(c12, 1, 2) EPI1(c13, 1, 3)
  EPI1(c20, 2, 0) EPI1(c21, 2, 1) EPI1(c22, 2, 2) EPI1(c23, 2, 3)
  EPI1(c30, 3, 0) EPI1(c31, 3, 1) EPI1(c32, 3, 2) EPI1(c33, 3, 3)
#undef EPI1
}

// ------------------------------------------------ LN: one wave per 512-row
__global__ __launch_bounds__(256) void ln_rows(
    const ushort* __restrict__ U, ushort* __restrict__ Z)
{
  const int row = blockIdx.x * 4 + (threadIdx.x >> 6);
  const int lane = threadIdx.x & 63;
  const size_t base = (size_t)row * 512 + lane * 8;
  const uint4 pk = *(const uint4*)(U + base);
  float v[8];
  v[0] = bf2f(pk.x & 0xffff); v[1] = bf2f(pk.x >> 16);
  v[2] = bf2f(pk.y & 0xffff); v[3] = bf2f(pk.y >> 16);
  v[4] = bf2f(pk.z & 0xffff); v[5] = bf2f(pk.z >> 16);
  v[6] = bf2f(pk.w & 0xffff); v[7] = bf2f(pk.w >> 16);
  float s = 0.f, s2 = 0.f;
#pragma unroll
  for (int j = 0; j < 8; ++j) { s += v[j]; s2 += v[j] * v[j]; }
#pragma unroll
  for (int m = 1; m < 64; m <<= 1) { s += __shfl_xor(s, m); s2 += __shfl_xor(s2, m); }
  const float mean = s * (1.f / 512.f);
  const float var = s2 * (1.f / 512.f) - mean * mean;
  const float inv = rsqrtf(var + 1e-5f);
  uint4 o;
  o.x = (uint)f2bf((v[0] - mean) * inv) | ((uint)f2bf((v[1] - mean) * inv) << 16);
  o.y = (uint)f2bf((v[2] - mean) * inv) | ((uint)f2bf((v[3] - mean) * inv) << 16);
  o.z = (uint)f2bf((v[4] - mean) * inv) | ((uint)f2bf((v[5] - mean) * inv) << 16);
  o.w = (uint)f2bf((v[6] - mean) * inv) | ((uint)f2bf((v[7] - mean) * inv) << 16);
  *(uint4*)(Z + base) = o;
}

// ------------------------------------------------ K2 (r12-proven, unchanged)
__global__ __launch_bounds__(256, 2) void k2_mfma(
    const ushort* __restrict__ Z, const ushort* __restrict__ Wt,
    const ushort* __restrict__ IL,
    const float* __restrict__ biv, const float* __restrict__ bfv,
    const float* __restrict__ bcv,
    ushort* __restrict__ G2, int tc, int Tc, int nwg)
{
  __shared__ __align__(16) short As[128 * 64];
  __shared__ __align__(16) short Bs0[128 * 64];
  __shared__ __align__(16) short Bs1[128 * 64];
  const int tid = threadIdx.x;
  const int lane = tid & 63, wid = tid >> 6;
  const int cpx = nwg >> 3;
  const int orig = blockIdx.x;
  const int swz = (orig & 7) * cpx + (orig >> 3);
  const int bx = swz % 6, by = swz / 6;
  const int nb = Tc >> 7;
  const int b = by / nb, tb = by % nb;
  const int r0g = b * 1024 + tc + tb * 128;
  const int r0c = b * Tc + tb * 128;
  const bool isig = bx < 4;
  const int n0 = isig ? bx * 128 : 0;
  const int fb = bx - 4;
  const int wr = wid >> 1, wc = wid & 1;
  const int fr = lane & 15, fq = lane >> 4;
  const int lr = lane >> 3;
  const int swz_el = ((lane & 7) ^ lr) * 8;

  const int R0 = r0g + wid * 32 + lr;
  const ushort* pa0 = Z + (size_t)(R0)      * 512 + swz_el;
  const ushort* pa1 = Z + (size_t)(R0 + 8)  * 512 + swz_el;
  const ushort* pa2 = Z + (size_t)(R0 + 16) * 512 + swz_el;
  const ushort* pa3 = Z + (size_t)(R0 + 24) * 512 + swz_el;
  const ushort* ph0 = ((((R0)      & 1023) == 0) ? IL : (Z + (size_t)(R0 - 1)  * 512)) + swz_el;
  const ushort* ph1 = ((((R0 + 8)  & 1023) == 0) ? IL : (Z + (size_t)(R0 + 7)  * 512)) + swz_el;
  const ushort* ph2 = ((((R0 + 16) & 1023) == 0) ? IL : (Z + (size_t)(R0 + 15) * 512)) + swz_el;
  const ushort* ph3 = ((((R0 + 24) & 1023) == 0) ? IL : (Z + (size_t)(R0 + 23) * 512)) + swz_el;
  const int RB0 = (isig ? n0 : 512 + fb * 256) + wid * 32 + lr;
  const ushort* pb0 = Wt + (size_t)(RB0)      * 1024 + swz_el;
  const ushort* pb1 = Wt + (size_t)(RB0 + 8)  * 1024 + swz_el;
  const ushort* pb2 = Wt + (size_t)(RB0 + 16) * 1024 + swz_el;
  const ushort* pb3 = Wt + (size_t)(RB0 + 24) * 1024 + swz_el;
  const int RB1 = (isig ? 1024 + n0 : 512 + fb * 256 + 128) + wid * 32 + lr;
  const ushort* pq0 = Wt + (size_t)(RB1)      * 1024 + swz_el;
  const ushort* pq1 = Wt + (size_t)(RB1 + 8)  * 1024 + swz_el;
  const ushort* pq2 = Wt + (size_t)(RB1 + 16) * 1024 + swz_el;
  const ushort* pq3 = Wt + (size_t)(RB1 + 24) * 1024 + swz_el;

  const int so0 = fr * 64 + ((fq)     ^ (fr & 7)) * 8;
  const int so1 = fr * 64 + ((4 + fq) ^ (fr & 7)) * 8;

  f32x4 zz = {0.f,0.f,0.f,0.f};
  f32x4 c00=zz,c01=zz,c02=zz,c03=zz, c10=zz,c11=zz,c12=zz,c13=zz,
        c20=zz,c21=zz,c22=zz,c23=zz, c30=zz,c31=zz,c32=zz,c33=zz;
  f32x4 d00=zz,d01=zz,d02=zz,d03=zz, d10=zz,d11=zz,d12=zz,d13=zz,
        d20=zz,d21=zz,d22=zz,d23=zz, d30=zz,d31=zz,d32=zz,d33=zz;

#define STG8(P0,P1,P2,P3, KO, DST) { \
    char* d_ = (char*)(DST) + wid * 4096; \
    gload_lds16((P0) + (KO), d_);        gload_lds16((P1) + (KO), d_ + 1024); \
    gload_lds16((P2) + (KO), d_ + 2048); gload_lds16((P3) + (KO), d_ + 3072); }

#define RDA(SO) \
    const s16x8 fa0 = *(const s16x8*)&As[wr * 4096 + 0 * 1024 + (SO)]; \
    const s16x8 fa1 = *(const s16x8*)&As[wr * 4096 + 1 * 1024 + (SO)]; \
    const s16x8 fa2 = *(const s16x8*)&As[wr * 4096 + 2 * 1024 + (SO)]; \
    const s16x8 fa3 = *(const s16x8*)&As[wr * 4096 + 3 * 1024 + (SO)];

#define RDB(BS, SO) \
    const s16x8 fb0 = *(const s16x8*)&(BS)[wc * 4096 + 0 * 1024 + (SO)]; \
    const s16x8 fb1 = *(const s16x8*)&(BS)[wc * 4096 + 1 * 1024 + (SO)]; \
    const s16x8 fb2 = *(const s16x8*)&(BS)[wc * 4096 + 2 * 1024 + (SO)]; \
    const s16x8 fb3 = *(const s16x8*)&(BS)[wc * 4096 + 3 * 1024 + (SO)];

#define MMC \
    MF(c00,fa0,fb0) MF(c01,fa0,fb1) MF(c02,fa0,fb2) MF(c03,fa0,fb3) \
    MF(c10,fa1,fb0) MF(c11,fa1,fb1) MF(c12,fa1,fb2) MF(c13,fa1,fb3) \
    MF(c20,fa2,fb0) MF(c21,fa2,fb1) MF(c22,fa2,fb2) MF(c23,fa2,fb3) \
    MF(c30,fa3,fb0) MF(c31,fa3,fb1) MF(c32,fa3,fb2) MF(c33,fa3,fb3)

#define MMD \
    MF(d00,fa0,fb0) MF(d01,fa0,fb1) MF(d02,fa0,fb2) MF(d03,fa0,fb3) \
    MF(d10,fa1,fb0) MF(d11,fa1,fb1) MF(d12,fa1,fb2) MF(d13,fa1,fb3) \
    MF(d20,fa2,fb0) MF(d21,fa2,fb1) MF(d22,fa2,fb2) MF(d23,fa2,fb3) \
    MF(d30,fa3,fb0) MF(d31,fa3,fb1) MF(d32,fa3,fb2) MF(d33,fa3,fb3)

#define KSTEP(SO_) { \
    RDA(SO_) \
    { RDB(Bs0, SO_) MMC } \
    { RDB(Bs1, SO_) MMD } }

  for (int k0 = 0; k0 < 512; k0 += 64) {
    STG8(pa0, pa1, pa2, pa3, k0, As)
    STG8(pb0, pb1, pb2, pb3, k0, Bs0)
    STG8(pq0, pq1, pq2, pq3, k0, Bs1)
    __syncthreads();
    KSTEP(so0)
    KSTEP(so1)
    __syncthreads();
  }
  for (int k0 = 0; k0 < 512; k0 += 64) {
    STG8(ph0, ph1, ph2, ph3, k0, As)
    STG8(pb0, pb1, pb2, pb3, 512 + k0, Bs0)
    STG8(pq0, pq1, pq2, pq3, 512 + k0, Bs1)
    __syncthreads();
    KSTEP(so0)
    KSTEP(so1)
    __syncthreads();
  }
#undef KSTEP
#undef MMD
#undef MMC
#undef RDB
#undef RDA
#undef STG8

  if (isig) {
#define EPI(cmn, dmn, m_, n_) { \
    const int col = n0 + wc * 64 + n_ * 16 + fr; \
    const float bvi = biv[col], bvc = bcv[col]; \
    const int rbase = wr * 64 + m_ * 16 + fq * 4; \
    _Pragma("unroll") for (int j = 0; j < 4; ++j) { \
      const float iv = 1.f / (1.f + __expf(-(cmn[j] + bvi))); \
      const float gv = 2.f / (1.f + __expf(-2.f * (dmn[j] + bvc))) - 1.f; \
      G2[(size_t)(r0c + rbase + j) * 1024 + col] = f2h(iv * gv); } }
    EPI(c00, d00, 0, 0) EPI(c01, d01, 0, 1) EPI(c02, d02, 0, 2) EPI(c03, d03, 0, 3)
    EPI(c10, d10, 1, 0) EPI(c11, d11, 1, 1) EPI(c12, d12, 1, 2) EPI(c13, d13, 1, 3)
    EPI(c20, d20, 2, 0) EPI(c21, d21, 2, 1) EPI(c22, d22, 2, 2) EPI(c23, d23, 2, 3)
    EPI(c30, d30, 3, 0) EPI(c31, d31, 3, 1) EPI(c32, d32, 3, 2) EPI(c33, d33, 3, 3)
#undef EPI
  } else {
#define EPIF(cmn, m_, n_, COFF) { \
    const int col = fb * 256 + (COFF) + wc * 64 + n_ * 16 + fr; \
    const float bv = bfv[col]; \
    const int rbase = wr * 64 + m_ * 16 + fq * 4; \
    _Pragma("unroll") for (int j = 0; j < 4; ++j) { \
      const float fv = 1.f / (1.f + __expf(-(cmn[j] + bv))); \
      G2[(size_t)(r0c + rbase + j) * 1024 + 512 + col] = f2h(fv); } }
    EPIF(c00, 0, 0, 0) EPIF(c01, 0, 1, 0) EPIF(c02, 0, 2, 0) EPIF(c03, 0, 3, 0)
    EPIF(c10, 1, 0, 0) EPIF(c11, 1, 1, 0) EPIF(c12, 1, 2, 0) EPIF(c13, 1, 3, 0)
    EPIF(c20, 2, 0, 0) EPIF(c21, 2, 1, 0) EPIF(c22, 2, 2, 0) EPIF(c23, 2, 3, 0)
    EPIF(c30, 3, 0, 0) EPIF(c31, 3, 1, 0) EPIF(c32, 3, 2, 0) EPIF(c33, 3, 3, 0)
    EPIF(d00, 0, 0, 128) EPIF(d01, 0, 1, 128) EPIF(d02, 0, 2, 128) EPIF(d03, 0, 3, 128)
    EPIF(d10, 1, 0, 128) EPIF(d11, 1, 1, 128) EPIF(d12, 1, 2, 128) EPIF(d13, 1, 3, 128)
    EPIF(d20, 2, 0, 128) EPIF(d21, 2, 1, 128) EPIF(d22, 2, 2, 128) EPIF(d23, 2, 3, 128)
    EPIF(d30, 3, 0, 128) EPIF(d31, 3, 1, 128) EPIF(d32, 3, 2, 128) EPIF(d33, 3, 3, 128)
#undef EPIF
  }
}

// ------------------------------------------------ scan phase A (vectorized 2 l/thread)
__global__ __launch_bounds__(256) void k3a_seg(
    const ushort* __restrict__ G2, float* __restrict__ Aseg,
    float* __restrict__ Bseg, int Tc)
{
  const int l2 = threadIdx.x * 2;
  const int b = blockIdx.x, s = blockIdx.y;
  const int SEGc = Tc >> 6;
  const ushort* gb = G2 + ((size_t)(b * Tc + s * 64)) * 1024;
  float A0 = 1.f, A1 = 1.f, c0 = 0.f, c1 = 0.f;
#pragma unroll 8
  for (int j = 0; j < 64; ++j) {
    const uint Pp = *(const uint*)(gb + (size_t)j * 1024 + l2);
    const uint Fp = *(const uint*)(gb + (size_t)j * 1024 + 512 + l2);
    const float P0 = h2f((ushort)(Pp & 0xffff)), P1 = h2f((ushort)(Pp >> 16));
    const float F0 = h2f((ushort)(Fp & 0xffff)), F1 = h2f((ushort)(Fp >> 16));
    A0 *= F0; A1 *= F1;
    c0 = fmaf(F0, c0, P0); c1 = fmaf(F1, c1, P1);
  }
  const size_t o = (size_t)(b * SEGc + s) * 512 + l2;
  float2 av; av.x = A0; av.y = A1;
  float2 bv; bv.x = c0; bv.y = c1;
  *(float2*)(Aseg + o) = av;
  *(float2*)(Bseg + o) = bv;
}

// ------------------------------------------------ scan phase C (fused combine+emit)
__global__ __launch_bounds__(128) void k3c_emit(
    const ushort* __restrict__ G2, const ushort* __restrict__ Z,
    const float* __restrict__ Aseg, const float* __restrict__ Bseg,
    const float* __restrict__ initc, float* __restrict__ cbuf,
    float* __restrict__ out, int tc, int Tc)
{
  __shared__ float tile[128][65];
  const int tid = threadIdx.x;
  const int l0 = blockIdx.x * 128;
  const int b = blockIdx.y, s = blockIdx.z;
  const int SEGc = Tc >> 6;
  const int l = l0 + tid;

  float c = (tc == 0) ? initc[l] : cbuf[b * 512 + l];
#pragma unroll
  for (int sp = 0; sp < 15; ++sp) {
    const size_t o = (size_t)(b * SEGc + sp) * 512 + l;
    const float Av = Aseg[o], Bv = Bseg[o];
    c = (sp < s) ? fmaf(Av, c, Bv) : c;
  }

  const ushort* gb = G2 + ((size_t)(b * Tc + s * 64)) * 1024 + l;
  const ushort* zb = Z + ((size_t)(b * 1024 + tc + s * 64)) * 512 + l;
#pragma unroll 8
  for (int j = 0; j < 64; ++j) {
    const float P = h2f(gb[(size_t)j * 1024]);
    const float F = h2f(gb[(size_t)j * 1024 + 512]);
    const float zv = bf2f(zb[(size_t)j * 512]);
    c = fmaf(F, c, P);
    tile[tid][j] = sinf(zv) * c;
  }
  if (s == SEGc - 1) cbuf[b * 512 + l] = c;
  __syncthreads();
  const int col = tid & 63, rhalf = tid >> 6;
  const size_t obase = ((size_t)b * 512 + l0) * 1024 + (size_t)(tc + s * 64) + col;
#pragma unroll
  for (int p = 0; p < 64; ++p) {
    const int row = rhalf + p * 2;
    out[obase + (size_t)row * 1024] = tile[row][col];
  }
}

// ------------------------------------------------ launcher
extern "C" void kernel_launch(void* const* d_in, const int* in_sizes, int n_in,
                              void* d_out, int out_size, void* d_ws, size_t ws_size,
                              hipStream_t stream)
{
  const float* x  = (const float*)d_in[0];
  const float* W  = (const float*)d_in[1];
  const float* rb = (const float*)d_in[2];
  const float* wi = (const float*)d_in[3];
  const float* wf = (const float*)d_in[4];
  const float* wc = (const float*)d_in[5];
  const float* ri = (const float*)d_in[6];
  const float* rf = (const float*)d_in[7];
  const float* rc = (const float*)d_in[8];
  const float* bi = (const float*)d_in[9];
  const float* bfo = (const float*)d_in[10];
  const float* bc = (const float*)d_in[11];
  const float* il = (const float*)d_in[12];
  const float* ic = (const float*)d_in[13];
  float* out = (float*)d_out;

  char* ws = (char*)d_ws;
  size_t off = 0;
  auto alloc = [&](size_t bytes) -> void* {
    void* p = ws + off;
    off = (off + bytes + 255) & ~(size_t)255;
    return p;
  };
  ushort* z    = (ushort*)alloc((size_t)65536 * 512 * 2);   // 67.1 MB
  ushort* W1t  = (ushort*)alloc((size_t)512 * 512 * 2);
  ushort* W2t  = (ushort*)alloc((size_t)1536 * 1024 * 2);
  ushort* ilb  = (ushort*)alloc(512 * 2);
  float*  cbuf = (float*)alloc((size_t)64 * 512 * 4);
  float*  Aseg = (float*)alloc((size_t)64 * 16 * 512 * 4);  // 2 MB
  float*  Bseg = (float*)alloc((size_t)64 * 16 * 512 * 4);
  const size_t fixed_end = off;
  ushort* G2   = (ushort*)(ws + fixed_end);
  ushort* u    = (ushort*)d_out;                            // dead before k3c

  int Tc = 1024;
  while (Tc > 128 && fixed_end + (size_t)64 * Tc * 1024 * 2 > ws_size) Tc >>= 1;

  // prep (weights + il only; x is consumed directly by k1)
  prep_all<<<dim3(16, 16, 8), 256, 0, stream>>>(
      wi, ri, wf, rf, wc, rc, il, W, W2t, ilb, W1t);

  k1_mfma<<<dim3(2048), 256, 0, stream>>>(x, W1t, rb, u);
  ln_rows<<<16384, 256, 0, stream>>>(u, z);

  for (int tc = 0; tc < 1024; tc += Tc) {
    const int SEGc = Tc >> 6;
    const int nwg2 = 6 * 64 * (Tc >> 7);
    k2_mfma<<<dim3(nwg2), 256, 0, stream>>>(
        z, W2t, ilb, bi, bfo, bc, G2, tc, Tc, nwg2);
    k3a_seg<<<dim3(64, SEGc), 256, 0, stream>>>(G2, Aseg, Bseg, Tc);
    k3c_emit<<<dim3(4, 64, SEGc), 128, 0, stream>>>(
        G2, z, Aseg, Bseg, ic, cbuf, out, tc, Tc);
  }
}

// Round 18
// 505.659 us; speedup vs baseline: 1.2589x; 1.0085x over previous
//
#include <hip/hip_runtime.h>
#include <hip/hip_bf16.h>
#include <hip/hip_fp16.h>
#include <cstdint>
#include <cstddef>

// B=64, D=512, T=1024, L=512
// prep_all: weight transposes + il
// K1:    u = cos(x @ rff_w + b)  — A read directly from x fp32, in-kernel
//        LDS transpose; staging cvt via HW v_cvt_pk_bf16_f32 (inline asm,
//        catalog T12/m240: no builtin exists on gfx950)
// LN:    z = layernorm(u)
// K2:    uniform 6-block decomposition per 128-row tile (r12-proven)
// scan:  k3a summaries (vectorized) -> k3c (fused combine + emit + transpose)
//
// LESSONS: (r4-r6) acc arrays are NOT SROA-promoted -> NAMED accs. (r8) XOR
// swizzle both-sides -> bank conflicts 0. (r9 FAIL) loads across raw
// s_barriers race. (r10 FAIL) dbuf halved blocks/CU. (r14 FAIL) BM=64xBN=512
// fused-LN shape staging-bound. (r17 FAIL) __floats2bfloat162 not in ROCm 7.2
// -> inline-asm v_cvt_pk_bf16_f32.

typedef float f32x4 __attribute__((ext_vector_type(4)));
typedef short s16x8 __attribute__((ext_vector_type(8)));

__device__ __forceinline__ void gload_lds16(const void* g, void* l) {
  __builtin_amdgcn_global_load_lds(
      (const __attribute__((address_space(1))) void*)g,
      (__attribute__((address_space(3))) void*)l, 16, 0, 0);
}
__device__ __forceinline__ ushort f2bf(float f) {
  uint32_t u = __float_as_uint(f);
  return (ushort)((u + 0x7FFF + ((u >> 16) & 1)) >> 16);  // RNE
}
__device__ __forceinline__ uint pk2bf(float a, float b) {
  // HW packed cvt (RNE), catalog T12 recipe: no builtin on gfx950
  uint r;
  asm("v_cvt_pk_bf16_f32 %0, %1, %2" : "=v"(r) : "v"(a), "v"(b));
  return r;
}
__device__ __forceinline__ float bf2f(ushort s) {
  return __uint_as_float(((uint32_t)s) << 16);
}
__device__ __forceinline__ ushort f2h(float f) {
  return __half_as_ushort(__float2half(f));
}
__device__ __forceinline__ float h2f(ushort s) {
  return __half2float(__ushort_as_half(s));
}

#define MF(d, a, b) d = __builtin_amdgcn_mfma_f32_16x16x32_bf16(a, b, d, 0, 0, 0);

// ------------------------------------------------ prep: 6 gate weights + W1 + il
__global__ __launch_bounds__(256) void prep_all(
    const float* __restrict__ s0, const float* __restrict__ s1,
    const float* __restrict__ s2, const float* __restrict__ s3,
    const float* __restrict__ s4, const float* __restrict__ s5,
    const float* __restrict__ il, const float* __restrict__ W1,
    ushort* __restrict__ W2t, ushort* __restrict__ ilb,
    ushort* __restrict__ W1t)
{
  __shared__ float tile[32][33];
  const int z = blockIdx.z;
  if (z == 6) {
    if (blockIdx.x == 0 && blockIdx.y == 0) {
      ilb[threadIdx.x] = f2bf(il[threadIdx.x]);
      ilb[threadIdx.x + 256] = f2bf(il[threadIdx.x + 256]);
    }
    return;
  }
  const float* src = z == 0 ? s0 : z == 1 ? s1 : z == 2 ? s2
                   : z == 3 ? s3 : z == 4 ? s4 : z == 5 ? s5 : W1;
  ushort* dst = (z == 7) ? W1t
              : W2t + (size_t)(z >> 1) * 512 * 1024 + (z & 1) * 512;
  const int ld = (z == 7) ? 512 : 1024;
  const int c0 = blockIdx.x * 32, r0 = blockIdx.y * 32;
  const int tx = threadIdx.x & 31, ty = threadIdx.x >> 5;
#pragma unroll
  for (int i = 0; i < 4; ++i)
    tile[ty + i * 8][tx] = src[(size_t)(r0 + ty + i * 8) * 512 + c0 + tx];
  __syncthreads();
#pragma unroll
  for (int i = 0; i < 4; ++i)
    dst[(size_t)(c0 + ty + i * 8) * ld + r0 + tx] = f2bf(tile[tx][ty + i * 8]);
}

// ------------------------------------------------ K1: u = cos(x @ W1t^T + b)
__global__ __launch_bounds__(256, 2) void k1_mfma(
    const float* __restrict__ x, const ushort* __restrict__ Bt,
    const float* __restrict__ bias, ushort* __restrict__ U)
{
  __shared__ __align__(16) short As[128 * 64];
  __shared__ __align__(16) short Bs[128 * 64];
  const int tid = threadIdx.x;
  const int lane = tid & 63, wid = tid >> 6;
  const int orig = blockIdx.x;
  const int swz = (orig & 7) * 256 + (orig >> 3);
  const int n0 = (swz & 3) * 128, r0 = (swz >> 2) * 128;
  const int b = r0 >> 10, t0 = r0 & 1023;
  const int wr = wid >> 1, wc = wid & 1;
  const int fr = lane & 15, fq = lane >> 4;
  const int lr = lane >> 3;
  const int swz_el = ((lane & 7) ^ lr) * 8;

  const float* xb = x + ((size_t)b * 512) * 1024 + t0;
  const int tA = tid & 127, hA = tid >> 7;

  const int RB = n0 + wid * 32 + lr;
  const ushort* pb0 = Bt + (size_t)(RB)      * 512 + swz_el;
  const ushort* pb1 = Bt + (size_t)(RB + 8)  * 512 + swz_el;
  const ushort* pb2 = Bt + (size_t)(RB + 16) * 512 + swz_el;
  const ushort* pb3 = Bt + (size_t)(RB + 24) * 512 + swz_el;
  char* dB = (char*)Bs + wid * 4096;

  const int so0 = fr * 64 + ((fq)     ^ (fr & 7)) * 8;
  const int so1 = fr * 64 + ((4 + fq) ^ (fr & 7)) * 8;

  f32x4 c00 = {0.f,0.f,0.f,0.f}, c01 = c00, c02 = c00, c03 = c00,
        c10 = c00, c11 = c00, c12 = c00, c13 = c00,
        c20 = c00, c21 = c00, c22 = c00, c23 = c00,
        c30 = c00, c31 = c00, c32 = c00, c33 = c00;

  for (int k0 = 0; k0 < 512; k0 += 64) {
    gload_lds16(pb0 + k0, dB);        gload_lds16(pb1 + k0, dB + 1024);
    gload_lds16(pb2 + k0, dB + 2048); gload_lds16(pb3 + k0, dB + 3072);
#pragma unroll
    for (int q = 0; q < 4; ++q) {
      const int c = hA * 4 + q;
      const float* src = xb + (size_t)(k0 + c * 8) * 1024 + tA;
      const float v0 = src[0 * 1024], v1 = src[1 * 1024];
      const float v2 = src[2 * 1024], v3 = src[3 * 1024];
      const float v4 = src[4 * 1024], v5 = src[5 * 1024];
      const float v6 = src[6 * 1024], v7 = src[7 * 1024];
      uint4 o;
      o.x = pk2bf(v0, v1);
      o.y = pk2bf(v2, v3);
      o.z = pk2bf(v4, v5);
      o.w = pk2bf(v6, v7);
      *(uint4*)&As[tA * 64 + ((c ^ (tA & 7)) * 8)] = o;
    }
    __syncthreads();
    const s16x8 a00 = *(const s16x8*)&As[wr * 4096 + 0 * 1024 + so0];
    const s16x8 a01 = *(const s16x8*)&As[wr * 4096 + 0 * 1024 + so1];
    const s16x8 a10 = *(const s16x8*)&As[wr * 4096 + 1 * 1024 + so0];
    const s16x8 a11 = *(const s16x8*)&As[wr * 4096 + 1 * 1024 + so1];
    const s16x8 a20 = *(const s16x8*)&As[wr * 4096 + 2 * 1024 + so0];
    const s16x8 a21 = *(const s16x8*)&As[wr * 4096 + 2 * 1024 + so1];
    const s16x8 a30 = *(const s16x8*)&As[wr * 4096 + 3 * 1024 + so0];
    const s16x8 a31 = *(const s16x8*)&As[wr * 4096 + 3 * 1024 + so1];
    const s16x8 b00 = *(const s16x8*)&Bs[wc * 4096 + 0 * 1024 + so0];
    const s16x8 b01 = *(const s16x8*)&Bs[wc * 4096 + 0 * 1024 + so1];
    const s16x8 b10 = *(const s16x8*)&Bs[wc * 4096 + 1 * 1024 + so0];
    const s16x8 b11 = *(const s16x8*)&Bs[wc * 4096 + 1 * 1024 + so1];
    const s16x8 b20 = *(const s16x8*)&Bs[wc * 4096 + 2 * 1024 + so0];
    const s16x8 b21 = *(const s16x8*)&Bs[wc * 4096 + 2 * 1024 + so1];
    const s16x8 b30 = *(const s16x8*)&Bs[wc * 4096 + 3 * 1024 + so0];
    const s16x8 b31 = *(const s16x8*)&Bs[wc * 4096 + 3 * 1024 + so1];
    MF(c00, a00, b00) MF(c01, a00, b10) MF(c02, a00, b20) MF(c03, a00, b30)
    MF(c10, a10, b00) MF(c11, a10, b10) MF(c12, a10, b20) MF(c13, a10, b30)
    MF(c20, a20, b00) MF(c21, a20, b10) MF(c22, a20, b20) MF(c23, a20, b30)
    MF(c30, a30, b00) MF(c31, a30, b10) MF(c32, a30, b20) MF(c33, a30, b30)
    MF(c00, a01, b01) MF(c01, a01, b11) MF(c02, a01, b21) MF(c03, a01, b31)
    MF(c10, a11, b01) MF(c11, a11, b11) MF(c12, a11, b21) MF(c13, a11, b31)
    MF(c20, a21, b01) MF(c21, a21, b11) MF(c22, a21, b21) MF(c23, a21, b31)
    MF(c30, a31, b01) MF(c31, a31, b11) MF(c32, a31, b21) MF(c33, a31, b31)
    __syncthreads();
  }

#define EPI1(cmn, m_, n_) { \
    const int col = n0 + wc * 64 + n_ * 16 + fr; \
    const float bv = bias[col]; \
    const int rbase = r0 + wr * 64 + m_ * 16 + fq * 4; \
    _Pragma("unroll") for (int j = 0; j < 4; ++j) \
      U[(size_t)(rbase + j) * 512 + col] = f2bf(cosf(cmn[j] + bv)); }
  EPI1(c00, 0, 0) EPI1(c01, 0, 1) EPI1(c02, 0, 2) EPI1(c03, 0, 3)
  EPI1(c10, 1, 0) EPI1(c11, 1, 1) EPI1(c12, 1, 2) EPI1(c13, 1, 3)
  EPI1(c20, 2, 0) EPI1(c21, 2, 1) EPI1(c22, 2, 2) EPI1(c23, 2, 3)
  EPI1(c30, 3, 0) EPI1(c31, 3, 1) EPI1(c32, 3, 2) EPI1(c33, 3, 3)
#undef EPI1
}

// ------------------------------------------------ LN: one wave per 512-row
__global__ __launch_bounds__(256) void ln_rows(
    const ushort* __restrict__ U, ushort* __restrict__ Z)
{
  const int row = blockIdx.x * 4 + (threadIdx.x >> 6);
  const int lane = threadIdx.x & 63;
  const size_t base = (size_t)row * 512 + lane * 8;
  const uint4 pk = *(const uint4*)(U + base);
  float v[8];
  v[0] = bf2f(pk.x & 0xffff); v[1] = bf2f(pk.x >> 16);
  v[2] = bf2f(pk.y & 0xffff); v[3] = bf2f(pk.y >> 16);
  v[4] = bf2f(pk.z & 0xffff); v[5] = bf2f(pk.z >> 16);
  v[6] = bf2f(pk.w & 0xffff); v[7] = bf2f(pk.w >> 16);
  float s = 0.f, s2 = 0.f;
#pragma unroll
  for (int j = 0; j < 8; ++j) { s += v[j]; s2 += v[j] * v[j]; }
#pragma unroll
  for (int m = 1; m < 64; m <<= 1) { s += __shfl_xor(s, m); s2 += __shfl_xor(s2, m); }
  const float mean = s * (1.f / 512.f);
  const float var = s2 * (1.f / 512.f) - mean * mean;
  const float inv = rsqrtf(var + 1e-5f);
  uint4 o;
  o.x = pk2bf((v[0] - mean) * inv, (v[1] - mean) * inv);
  o.y = pk2bf((v[2] - mean) * inv, (v[3] - mean) * inv);
  o.z = pk2bf((v[4] - mean) * inv, (v[5] - mean) * inv);
  o.w = pk2bf((v[6] - mean) * inv, (v[7] - mean) * inv);
  *(uint4*)(Z + base) = o;
}

// ------------------------------------------------ K2 (r12-proven, unchanged)
__global__ __launch_bounds__(256, 2) void k2_mfma(
    const ushort* __restrict__ Z, const ushort* __restrict__ Wt,
    const ushort* __restrict__ IL,
    const float* __restrict__ biv, const float* __restrict__ bfv,
    const float* __restrict__ bcv,
    ushort* __restrict__ G2, int tc, int Tc, int nwg)
{
  __shared__ __align__(16) short As[128 * 64];
  __shared__ __align__(16) short Bs0[128 * 64];
  __shared__ __align__(16) short Bs1[128 * 64];
  const int tid = threadIdx.x;
  const int lane = tid & 63, wid = tid >> 6;
  const int cpx = nwg >> 3;
  const int orig = blockIdx.x;
  const int swz = (orig & 7) * cpx + (orig >> 3);
  const int bx = swz % 6, by = swz / 6;
  const int nb = Tc >> 7;
  const int b = by / nb, tb = by % nb;
  const int r0g = b * 1024 + tc + tb * 128;
  const int r0c = b * Tc + tb * 128;
  const bool isig = bx < 4;
  const int n0 = isig ? bx * 128 : 0;
  const int fb = bx - 4;
  const int wr = wid >> 1, wc = wid & 1;
  const int fr = lane & 15, fq = lane >> 4;
  const int lr = lane >> 3;
  const int swz_el = ((lane & 7) ^ lr) * 8;

  const int R0 = r0g + wid * 32 + lr;
  const ushort* pa0 = Z + (size_t)(R0)      * 512 + swz_el;
  const ushort* pa1 = Z + (size_t)(R0 + 8)  * 512 + swz_el;
  const ushort* pa2 = Z + (size_t)(R0 + 16) * 512 + swz_el;
  const ushort* pa3 = Z + (size_t)(R0 + 24) * 512 + swz_el;
  const ushort* ph0 = ((((R0)      & 1023) == 0) ? IL : (Z + (size_t)(R0 - 1)  * 512)) + swz_el;
  const ushort* ph1 = ((((R0 + 8)  & 1023) == 0) ? IL : (Z + (size_t)(R0 + 7)  * 512)) + swz_el;
  const ushort* ph2 = ((((R0 + 16) & 1023) == 0) ? IL : (Z + (size_t)(R0 + 15) * 512)) + swz_el;
  const ushort* ph3 = ((((R0 + 24) & 1023) == 0) ? IL : (Z + (size_t)(R0 + 23) * 512)) + swz_el;
  const int RB0 = (isig ? n0 : 512 + fb * 256) + wid * 32 + lr;
  const ushort* pb0 = Wt + (size_t)(RB0)      * 1024 + swz_el;
  const ushort* pb1 = Wt + (size_t)(RB0 + 8)  * 1024 + swz_el;
  const ushort* pb2 = Wt + (size_t)(RB0 + 16) * 1024 + swz_el;
  const ushort* pb3 = Wt + (size_t)(RB0 + 24) * 1024 + swz_el;
  const int RB1 = (isig ? 1024 + n0 : 512 + fb * 256 + 128) + wid * 32 + lr;
  const ushort* pq0 = Wt + (size_t)(RB1)      * 1024 + swz_el;
  const ushort* pq1 = Wt + (size_t)(RB1 + 8)  * 1024 + swz_el;
  const ushort* pq2 = Wt + (size_t)(RB1 + 16) * 1024 + swz_el;
  const ushort* pq3 = Wt + (size_t)(RB1 + 24) * 1024 + swz_el;

  const int so0 = fr * 64 + ((fq)     ^ (fr & 7)) * 8;
  const int so1 = fr * 64 + ((4 + fq) ^ (fr & 7)) * 8;

  f32x4 zz = {0.f,0.f,0.f,0.f};
  f32x4 c00=zz,c01=zz,c02=zz,c03=zz, c10=zz,c11=zz,c12=zz,c13=zz,
        c20=zz,c21=zz,c22=zz,c23=zz, c30=zz,c31=zz,c32=zz,c33=zz;
  f32x4 d00=zz,d01=zz,d02=zz,d03=zz, d10=zz,d11=zz,d12=zz,d13=zz,
        d20=zz,d21=zz,d22=zz,d23=zz, d30=zz,d31=zz,d32=zz,d33=zz;

#define STG8(P0,P1,P2,P3, KO, DST) { \
    char* d_ = (char*)(DST) + wid * 4096; \
    gload_lds16((P0) + (KO), d_);        gload_lds16((P1) + (KO), d_ + 1024); \
    gload_lds16((P2) + (KO), d_ + 2048); gload_lds16((P3) + (KO), d_ + 3072); }

#define RDA(SO) \
    const s16x8 fa0 = *(const s16x8*)&As[wr * 4096 + 0 * 1024 + (SO)]; \
    const s16x8 fa1 = *(const s16x8*)&As[wr * 4096 + 1 * 1024 + (SO)]; \
    const s16x8 fa2 = *(const s16x8*)&As[wr * 4096 + 2 * 1024 + (SO)]; \
    const s16x8 fa3 = *(const s16x8*)&As[wr * 4096 + 3 * 1024 + (SO)];

#define RDB(BS, SO) \
    const s16x8 fb0 = *(const s16x8*)&(BS)[wc * 4096 + 0 * 1024 + (SO)]; \
    const s16x8 fb1 = *(const s16x8*)&(BS)[wc * 4096 + 1 * 1024 + (SO)]; \
    const s16x8 fb2 = *(const s16x8*)&(BS)[wc * 4096 + 2 * 1024 + (SO)]; \
    const s16x8 fb3 = *(const s16x8*)&(BS)[wc * 4096 + 3 * 1024 + (SO)];

#define MMC \
    MF(c00,fa0,fb0) MF(c01,fa0,fb1) MF(c02,fa0,fb2) MF(c03,fa0,fb3) \
    MF(c10,fa1,fb0) MF(c11,fa1,fb1) MF(c12,fa1,fb2) MF(c13,fa1,fb3) \
    MF(c20,fa2,fb0) MF(c21,fa2,fb1) MF(c22,fa2,fb2) MF(c23,fa2,fb3) \
    MF(c30,fa3,fb0) MF(c31,fa3,fb1) MF(c32,fa3,fb2) MF(c33,fa3,fb3)

#define MMD \
    MF(d00,fa0,fb0) MF(d01,fa0,fb1) MF(d02,fa0,fb2) MF(d03,fa0,fb3) \
    MF(d10,fa1,fb0) MF(d11,fa1,fb1) MF(d12,fa1,fb2) MF(d13,fa1,fb3) \
    MF(d20,fa2,fb0) MF(d21,fa2,fb1) MF(d22,fa2,fb2) MF(d23,fa2,fb3) \
    MF(d30,fa3,fb0) MF(d31,fa3,fb1) MF(d32,fa3,fb2) MF(d33,fa3,fb3)

#define KSTEP(SO_) { \
    RDA(SO_) \
    { RDB(Bs0, SO_) MMC } \
    { RDB(Bs1, SO_) MMD } }

  for (int k0 = 0; k0 < 512; k0 += 64) {
    STG8(pa0, pa1, pa2, pa3, k0, As)
    STG8(pb0, pb1, pb2, pb3, k0, Bs0)
    STG8(pq0, pq1, pq2, pq3, k0, Bs1)
    __syncthreads();
    KSTEP(so0)
    KSTEP(so1)
    __syncthreads();
  }
  for (int k0 = 0; k0 < 512; k0 += 64) {
    STG8(ph0, ph1, ph2, ph3, k0, As)
    STG8(pb0, pb1, pb2, pb3, 512 + k0, Bs0)
    STG8(pq0, pq1, pq2, pq3, 512 + k0, Bs1)
    __syncthreads();
    KSTEP(so0)
    KSTEP(so1)
    __syncthreads();
  }
#undef KSTEP
#undef MMD
#undef MMC
#undef RDB
#undef RDA
#undef STG8

  if (isig) {
#define EPI(cmn, dmn, m_, n_) { \
    const int col = n0 + wc * 64 + n_ * 16 + fr; \
    const float bvi = biv[col], bvc = bcv[col]; \
    const int rbase = wr * 64 + m_ * 16 + fq * 4; \
    _Pragma("unroll") for (int j = 0; j < 4; ++j) { \
      const float iv = 1.f / (1.f + __expf(-(cmn[j] + bvi))); \
      const float gv = 2.f / (1.f + __expf(-2.f * (dmn[j] + bvc))) - 1.f; \
      G2[(size_t)(r0c + rbase + j) * 1024 + col] = f2h(iv * gv); } }
    EPI(c00, d00, 0, 0) EPI(c01, d01, 0, 1) EPI(c02, d02, 0, 2) EPI(c03, d03, 0, 3)
    EPI(c10, d10, 1, 0) EPI(c11, d11, 1, 1) EPI(c12, d12, 1, 2) EPI(c13, d13, 1, 3)
    EPI(c20, d20, 2, 0) EPI(c21, d21, 2, 1) EPI(c22, d22, 2, 2) EPI(c23, d23, 2, 3)
    EPI(c30, d30, 3, 0) EPI(c31, d31, 3, 1) EPI(c32, d32, 3, 2) EPI(c33, d33, 3, 3)
#undef EPI
  } else {
#define EPIF(cmn, m_, n_, COFF) { \
    const int col = fb * 256 + (COFF) + wc * 64 + n_ * 16 + fr; \
    const float bv = bfv[col]; \
    const int rbase = wr * 64 + m_ * 16 + fq * 4; \
    _Pragma("unroll") for (int j = 0; j < 4; ++j) { \
      const float fv = 1.f / (1.f + __expf(-(cmn[j] + bv))); \
      G2[(size_t)(r0c + rbase + j) * 1024 + 512 + col] = f2h(fv); } }
    EPIF(c00, 0, 0, 0) EPIF(c01, 0, 1, 0) EPIF(c02, 0, 2, 0) EPIF(c03, 0, 3, 0)
    EPIF(c10, 1, 0, 0) EPIF(c11, 1, 1, 0) EPIF(c12, 1, 2, 0) EPIF(c13, 1, 3, 0)
    EPIF(c20, 2, 0, 0) EPIF(c21, 2, 1, 0) EPIF(c22, 2, 2, 0) EPIF(c23, 2, 3, 0)
    EPIF(c30, 3, 0, 0) EPIF(c31, 3, 1, 0) EPIF(c32, 3, 2, 0) EPIF(c33, 3, 3, 0)
    EPIF(d00, 0, 0, 128) EPIF(d01, 0, 1, 128) EPIF(d02, 0, 2, 128) EPIF(d03, 0, 3, 128)
    EPIF(d10, 1, 0, 128) EPIF(d11, 1, 1, 128) EPIF(d12, 1, 2, 128) EPIF(d13, 1, 3, 128)
    EPIF(d20, 2, 0, 128) EPIF(d21, 2, 1, 128) EPIF(d22, 2, 2, 128) EPIF(d23, 2, 3, 128)
    EPIF(d30, 3, 0, 128) EPIF(d31, 3, 1, 128) EPIF(d32, 3, 2, 128) EPIF(d33, 3, 3, 128)
#undef EPIF
  }
}

// ------------------------------------------------ scan phase A (vectorized)
__global__ __launch_bounds__(256) void k3a_seg(
    const ushort* __restrict__ G2, float* __restrict__ Aseg,
    float* __restrict__ Bseg, int Tc)
{
  const int l2 = threadIdx.x * 2;
  const int b = blockIdx.x, s = blockIdx.y;
  const int SEGc = Tc >> 6;
  const ushort* gb = G2 + ((size_t)(b * Tc + s * 64)) * 1024;
  float A0 = 1.f, A1 = 1.f, c0 = 0.f, c1 = 0.f;
#pragma unroll 8
  for (int j = 0; j < 64; ++j) {
    const uint Pp = *(const uint*)(gb + (size_t)j * 1024 + l2);
    const uint Fp = *(const uint*)(gb + (size_t)j * 1024 + 512 + l2);
    const float P0 = h2f((ushort)(Pp & 0xffff)), P1 = h2f((ushort)(Pp >> 16));
    const float F0 = h2f((ushort)(Fp & 0xffff)), F1 = h2f((ushort)(Fp >> 16));
    A0 *= F0; A1 *= F1;
    c0 = fmaf(F0, c0, P0); c1 = fmaf(F1, c1, P1);
  }
  const size_t o = (size_t)(b * SEGc + s) * 512 + l2;
  float2 av; av.x = A0; av.y = A1;
  float2 bv; bv.x = c0; bv.y = c1;
  *(float2*)(Aseg + o) = av;
  *(float2*)(Bseg + o) = bv;
}

// ------------------------------------------------ scan phase C (fused combine+emit)
__global__ __launch_bounds__(128) void k3c_emit(
    const ushort* __restrict__ G2, const ushort* __restrict__ Z,
    const float* __restrict__ Aseg, const float* __restrict__ Bseg,
    const float* __restrict__ initc, float* __restrict__ cbuf,
    float* __restrict__ out, int tc, int Tc)
{
  __shared__ float tile[128][65];
  const int tid = threadIdx.x;
  const int l0 = blockIdx.x * 128;
  const int b = blockIdx.y, s = blockIdx.z;
  const int SEGc = Tc >> 6;
  const int l = l0 + tid;

  float c = (tc == 0) ? initc[l] : cbuf[b * 512 + l];
#pragma unroll
  for (int sp = 0; sp < 15; ++sp) {
    const size_t o = (size_t)(b * SEGc + sp) * 512 + l;
    const float Av = Aseg[o], Bv = Bseg[o];
    c = (sp < s) ? fmaf(Av, c, Bv) : c;
  }

  const ushort* gb = G2 + ((size_t)(b * Tc + s * 64)) * 1024 + l;
  const ushort* zb = Z + ((size_t)(b * 1024 + tc + s * 64)) * 512 + l;
#pragma unroll 8
  for (int j = 0; j < 64; ++j) {
    const float P = h2f(gb[(size_t)j * 1024]);
    const float F = h2f(gb[(size_t)j * 1024 + 512]);
    const float zv = bf2f(zb[(size_t)j * 512]);
    c = fmaf(F, c, P);
    tile[tid][j] = sinf(zv) * c;
  }
  if (s == SEGc - 1) cbuf[b * 512 + l] = c;
  __syncthreads();
  const int col = tid & 63, rhalf = tid >> 6;
  const size_t obase = ((size_t)b * 512 + l0) * 1024 + (size_t)(tc + s * 64) + col;
#pragma unroll
  for (int p = 0; p < 64; ++p) {
    const int row = rhalf + p * 2;
    out[obase + (size_t)row * 1024] = tile[row][col];
  }
}

// ------------------------------------------------ launcher
extern "C" void kernel_launch(void* const* d_in, const int* in_sizes, int n_in,
                              void* d_out, int out_size, void* d_ws, size_t ws_size,
                              hipStream_t stream)
{
  const float* x  = (const float*)d_in[0];
  const float* W  = (const float*)d_in[1];
  const float* rb = (const float*)d_in[2];
  const float* wi = (const float*)d_in[3];
  const float* wf = (const float*)d_in[4];
  const float* wc = (const float*)d_in[5];
  const float* ri = (const float*)d_in[6];
  const float* rf = (const float*)d_in[7];
  const float* rc = (const float*)d_in[8];
  const float* bi = (const float*)d_in[9];
  const float* bfo = (const float*)d_in[10];
  const float* bc = (const float*)d_in[11];
  const float* il = (const float*)d_in[12];
  const float* ic = (const float*)d_in[13];
  float* out = (float*)d_out;

  char* ws = (char*)d_ws;
  size_t off = 0;
  auto alloc = [&](size_t bytes) -> void* {
    void* p = ws + off;
    off = (off + bytes + 255) & ~(size_t)255;
    return p;
  };
  ushort* z    = (ushort*)alloc((size_t)65536 * 512 * 2);   // 67.1 MB
  ushort* W1t  = (ushort*)alloc((size_t)512 * 512 * 2);
  ushort* W2t  = (ushort*)alloc((size_t)1536 * 1024 * 2);
  ushort* ilb  = (ushort*)alloc(512 * 2);
  float*  cbuf = (float*)alloc((size_t)64 * 512 * 4);
  float*  Aseg = (float*)alloc((size_t)64 * 16 * 512 * 4);  // 2 MB
  float*  Bseg = (float*)alloc((size_t)64 * 16 * 512 * 4);
  const size_t fixed_end = off;
  ushort* G2   = (ushort*)(ws + fixed_end);
  ushort* u    = (ushort*)d_out;                            // dead before k3c

  int Tc = 1024;
  while (Tc > 128 && fixed_end + (size_t)64 * Tc * 1024 * 2 > ws_size) Tc >>= 1;

  prep_all<<<dim3(16, 16, 8), 256, 0, stream>>>(
      wi, ri, wf, rf, wc, rc, il, W, W2t, ilb, W1t);

  k1_mfma<<<dim3(2048), 256, 0, stream>>>(x, W1t, rb, u);
  ln_rows<<<16384, 256, 0, stream>>>(u, z);

  for (int tc = 0; tc < 1024; tc += Tc) {
    const int SEGc = Tc >> 6;
    const int nwg2 = 6 * 64 * (Tc >> 7);
    k2_mfma<<<dim3(nwg2), 256, 0, stream>>>(
        z, W2t, ilb, bi, bfo, bc, G2, tc, Tc, nwg2);
    k3a_seg<<<dim3(64, SEGc), 256, 0, stream>>>(G2, Aseg, Bseg, Tc);
    k3c_emit<<<dim3(4, 64, SEGc), 128, 0, stream>>>(
        G2, z, Aseg, Bseg, ic, cbuf, out, tc, Tc);
  }
}